// Round 9
// baseline (334.707 us; speedup 1.0000x reference)
//
#include <hip/hip_runtime.h>
#include <hip/hip_bf16.h>
#include <cstdint>

typedef __attribute__((ext_vector_type(8))) short bf16x8;
typedef __attribute__((ext_vector_type(4))) float f32x4;

__device__ inline uint16_t f2bf(float f) {
  uint32_t u = __float_as_uint(f);
  u += 0x7FFF + ((u >> 16) & 1);          // round-to-nearest-even
  return (uint16_t)(u >> 16);
}

// ---------------- prep1: s_feat (RMS-normalized), rgb coefs ----------------
__global__ __launch_bounds__(256) void prep1_kernel(
    const float* __restrict__ w,        // (2,512)
    const float* __restrict__ afw,      // (128,512)
    const float* __restrict__ afb,      // (128)
    const float* __restrict__ argbw,    // (128,512)
    const float* __restrict__ argbb,    // (128)
    const float* __restrict__ wrgb,     // (3,128)
    const float* __restrict__ ema_r,    // (1)
    float* __restrict__ s_feat_out,     // (2,128)
    float* __restrict__ coef_out)       // (2,3,128)
{
  __shared__ float sfeat_s[256];
  __shared__ float srgb_s[256];
  __shared__ float sred[256];
  const int tid = threadIdx.x, lane = tid & 63, wv = tid >> 6;
  const float wg = 0.04419417382415922f;    // 1/sqrt(512)
  #pragma unroll 2
  for (int p = wv; p < 256; p += 4) {
    const int bb = p >> 7, c = p & 127;
    float d1 = 0.f, d2 = 0.f;
    #pragma unroll
    for (int it = 0; it < 8; ++it) {
      const int k = lane + 64*it;
      const float wvv = w[bb*512 + k];
      d1 += wvv * afw[c*512 + k];
      d2 += wvv * argbw[c*512 + k];
    }
    #pragma unroll
    for (int off = 32; off; off >>= 1) {
      d1 += __shfl_xor(d1, off, 64);
      d2 += __shfl_xor(d2, off, 64);
    }
    if (lane == 0) {
      sfeat_s[p] = d1 * wg + afb[c];
      srgb_s[p]  = (d2 * wg + argbb[c]) * 0.08838834764831845f * rsqrtf(ema_r[0]);
    }
  }
  __syncthreads();
  const float sf = sfeat_s[tid];
  sred[tid] = sf * sf;
  __syncthreads();
  for (int off = 128; off > 0; off >>= 1) {
    if (tid < off) sred[tid] += sred[tid + off];
    __syncthreads();
  }
  const float snorm = rsqrtf(sred[0] * (1.0f/256.0f));
  s_feat_out[tid] = sf * snorm;
  for (int e = tid; e < 768; e += 256) {
    int bb = e / 384, o = (e % 384) / 128, i = e & 127;
    coef_out[e] = wrgb[o*128 + i] * srgb_s[bb*128 + i];
  }
}

// ---------------- prep2: wnscale (inline) + modulate + demod -> bf16 fragments ----------------
// wfrag layout: [b][kidx 0..35][mglob 0..7][lane 0..63][j 0..7]  (short/bf16)
__global__ __launch_bounds__(128) void prep2_kernel(
    const float* __restrict__ wfeat, const float* __restrict__ s_feat,
    const float* __restrict__ ema_f, short* __restrict__ wfrag)
{
  __shared__ float red[128];
  const int bo = blockIdx.x, b = bo >> 7, o = bo & 127;
  const int i = threadIdx.x;
  float wraw[9]; float ssr = 0.f;
  #pragma unroll
  for (int j = 0; j < 9; ++j) { wraw[j] = wfeat[(o*128 + i)*9 + j]; ssr += wraw[j]*wraw[j]; }
  red[i] = ssr; __syncthreads();
  for (int off = 64; off > 0; off >>= 1) { if (i < off) red[i] += red[i+off]; __syncthreads(); }
  const float wsc = rsqrtf(red[0] * (1.0f/1152.0f));
  const float sv = s_feat[b*128 + i];
  float wr[9]; float ss = 0.f;
  #pragma unroll
  for (int j = 0; j < 9; ++j) { wr[j] = wraw[j] * wsc * sv; ss += wr[j]*wr[j]; }
  __syncthreads();
  red[i] = ss; __syncthreads();
  for (int off = 64; off > 0; off >>= 1) { if (i < off) red[i] += red[i+off]; __syncthreads(); }
  const float d = rsqrtf(red[0] + 1e-8f) * rsqrtf(ema_f[0]);
  const int chunk = i >> 5;
  const int lane = (o & 15) | (((i >> 3) & 3) << 4);
  const int jj = i & 7;
  #pragma unroll
  for (int tap = 0; tap < 9; ++tap) {
    int kidx = chunk*9 + tap;
    size_t sidx = ((((size_t)b*36 + kidx)*8 + (o >> 4)) << 9) + (lane << 3) + jj;
    wfrag[sidx] = (short)f2bf(wr[tap] * d);
  }
}

// ---------------- conv via bf16 MFMA implicit GEMM ----------------
// 34-col LDS window (52.2 KB -> 3 blocks/CU) + software-pipelined xf AND wf (2 banks).
// LDS x layout: unit(r,g,c) = 16B (8 ic), addr = ((r*16+g)*34 + c)*16; col c <-> gx = x0-2+c.
__global__ __launch_bounds__(256, 3) void conv_mfma_kernel(
    const float* __restrict__ x, const short* __restrict__ wfrag,
    const float* __restrict__ bias_feat, float* __restrict__ conv_out)
{
  __shared__ __align__(16) char xls[52224];
  __shared__ float bias_lds[128];
  const int tid = threadIdx.x;
  const int bx = blockIdx.x, by = blockIdx.y, b = blockIdx.z;
  const int x0 = bx * 32, y0 = by * 4;
  if (tid < 128) bias_lds[tid] = bias_feat[tid];

  const f32x4 f4z = {0.f, 0.f, 0.f, 0.f};
  const float* xb = x + (size_t)b * 8388608;

  // ---- stage x tile: 128 ic x 6 r x 34 c (fp32 -> bf16 pairs) ----
  {
    const int sl = tid & 7, pL = tid >> 3;              // sl: float4 slot, pL: ic-pair 0..31
    const int gxm = x0 + 4*sl;                          // main cols 2+4sl .. 5+4sl
    const bool xokm = (unsigned)gxm <= 252u;
    const int gxe = x0 - 2;
    #pragma unroll
    for (int r = 0; r < 6; ++r) {
      const int gy = y0 - 2 + r;
      const bool yok = (unsigned)gy < 256u;
      #pragma unroll
      for (int ph = 0; ph < 2; ++ph) {
        const int p = pL + 32*ph;                       // ic pair 0..63
        const float* s0 = xb + (size_t)(2*p)*65536 + gy*256 + gxm;
        const bool ok = yok && xokm;
        f32x4 v0 = ok ? *(const f32x4*)s0 : f4z;
        f32x4 v1 = ok ? *(const f32x4*)(s0 + 65536) : f4z;
        char* wb = xls + (size_t)(((r*16 + (p>>2))*34 + 2 + 4*sl)*16 + (p&3)*4);
        #pragma unroll
        for (int i2 = 0; i2 < 4; ++i2) {
          uint32_t pk = ((uint32_t)f2bf(v1[i2]) << 16) | f2bf(v0[i2]);
          *(uint32_t*)(wb + i2*16) = pk;
        }
        if (sl == 0) {                                  // edge cols 0,1 (gx = x0-2, x0-1)
          const bool eok = yok && (gxe >= 0);
          const float* e0 = xb + (size_t)(2*p)*65536 + gy*256 + gxe;
          float e00 = eok ? e0[0] : 0.f, e01 = eok ? e0[1] : 0.f;
          float e10 = eok ? e0[65536] : 0.f, e11 = eok ? e0[65537] : 0.f;
          char* eb = xls + (size_t)(((r*16 + (p>>2))*34)*16 + (p&3)*4);
          *(uint32_t*)eb        = ((uint32_t)f2bf(e10) << 16) | f2bf(e00);
          *(uint32_t*)(eb + 16) = ((uint32_t)f2bf(e11) << 16) | f2bf(e01);
        }
      }
    }
  }
  __syncthreads();

  // ---- K-loop: 36 kidx; xf (LDS) and wf (global) both 2-bank software-pipelined ----
  const int lane = tid & 63, wave = tid >> 6;
  const int wp = wave & 1, wo = wave >> 1;
  const int l15 = lane & 15, lq = lane >> 4;
  const short* wbase = wfrag + ((size_t)b*288 + wo*4)*512 + (size_t)lane*8;
  const int abase = ((wp*32 + lq)*34 + l15)*16;

  f32x4 acc[4][4] = {};
  bf16x8 wfA[4], wfB[4], xfA[4], xfB[4];

#define LDW(KI, WF) { const short* wp_ = wbase + (size_t)(KI)*4096;          \
    WF[0] = *(const bf16x8*)(wp_);       WF[1] = *(const bf16x8*)(wp_+512);  \
    WF[2] = *(const bf16x8*)(wp_+1024);  WF[3] = *(const bf16x8*)(wp_+1536); }

#define LDX(KI, XF) { const int ch_ = (KI)/9, tp_ = (KI)%9, ky_ = tp_/3, kx_ = tp_%3; \
    const int o00 = ((ky_*16 + ch_*4)*34 + kx_)*16;                           \
    const int o10 = o00 + 8704;                         /* +1 row = 16*34*16 */ \
    XF[0] = *(const bf16x8*)(xls + abase + o00);                              \
    XF[1] = *(const bf16x8*)(xls + abase + o00 + 256);                        \
    XF[2] = *(const bf16x8*)(xls + abase + o10);                              \
    XF[3] = *(const bf16x8*)(xls + abase + o10 + 256); }

#define MF(XF, WF) {                                                          \
    __builtin_amdgcn_s_setprio(1);                                            \
    acc[0][0] = __builtin_amdgcn_mfma_f32_16x16x32_bf16(XF[0], WF[0], acc[0][0], 0,0,0); \
    acc[0][1] = __builtin_amdgcn_mfma_f32_16x16x32_bf16(XF[0], WF[1], acc[0][1], 0,0,0); \
    acc[0][2] = __builtin_amdgcn_mfma_f32_16x16x32_bf16(XF[0], WF[2], acc[0][2], 0,0,0); \
    acc[0][3] = __builtin_amdgcn_mfma_f32_16x16x32_bf16(XF[0], WF[3], acc[0][3], 0,0,0); \
    acc[1][0] = __builtin_amdgcn_mfma_f32_16x16x32_bf16(XF[1], WF[0], acc[1][0], 0,0,0); \
    acc[1][1] = __builtin_amdgcn_mfma_f32_16x16x32_bf16(XF[1], WF[1], acc[1][1], 0,0,0); \
    acc[1][2] = __builtin_amdgcn_mfma_f32_16x16x32_bf16(XF[1], WF[2], acc[1][2], 0,0,0); \
    acc[1][3] = __builtin_amdgcn_mfma_f32_16x16x32_bf16(XF[1], WF[3], acc[1][3], 0,0,0); \
    acc[2][0] = __builtin_amdgcn_mfma_f32_16x16x32_bf16(XF[2], WF[0], acc[2][0], 0,0,0); \
    acc[2][1] = __builtin_amdgcn_mfma_f32_16x16x32_bf16(XF[2], WF[1], acc[2][1], 0,0,0); \
    acc[2][2] = __builtin_amdgcn_mfma_f32_16x16x32_bf16(XF[2], WF[2], acc[2][2], 0,0,0); \
    acc[2][3] = __builtin_amdgcn_mfma_f32_16x16x32_bf16(XF[2], WF[3], acc[2][3], 0,0,0); \
    acc[3][0] = __builtin_amdgcn_mfma_f32_16x16x32_bf16(XF[3], WF[0], acc[3][0], 0,0,0); \
    acc[3][1] = __builtin_amdgcn_mfma_f32_16x16x32_bf16(XF[3], WF[1], acc[3][1], 0,0,0); \
    acc[3][2] = __builtin_amdgcn_mfma_f32_16x16x32_bf16(XF[3], WF[2], acc[3][2], 0,0,0); \
    acc[3][3] = __builtin_amdgcn_mfma_f32_16x16x32_bf16(XF[3], WF[3], acc[3][3], 0,0,0); \
    __builtin_amdgcn_s_setprio(0); }

  LDX(0, xfA); LDW(0, wfA);
  LDX(1, xfB); LDW(1, wfB);
  #pragma unroll
  for (int kk = 0; kk < 36; kk += 2) {
    MF(xfA, wfA);
    if (kk + 2 < 36) { LDX(kk + 2, xfA); LDW(kk + 2, wfA); }
    MF(xfB, wfB);
    if (kk + 3 < 36) { LDX(kk + 3, xfB); LDW(kk + 3, wfB); }
  }
#undef LDW
#undef LDX
#undef MF

  // ---- epilogue: lane holds px = x0+(p&1)*16+lq*4+j (contig), oc = wo*64+o*16+l15 ----
  #pragma unroll
  for (int p = 0; p < 4; ++p) {
    const int py = y0 + wp*2 + (p>>1);
    if (py >= 258) continue;
    const int px0 = x0 + (p&1)*16 + lq*4;
    #pragma unroll
    for (int o = 0; o < 4; ++o) {
      const int oc = wo*64 + o*16 + l15;
      const float bz = bias_lds[oc];
      f32x4 v = acc[p][o];
      v[0] += bz; v[1] += bz; v[2] += bz; v[3] += bz;
      float* dst = conv_out + ((size_t)(b*128 + oc)*258 + py)*258 + px0;
      if (px0 <= 254) {
        *(f32x4*)dst = v;
      } else {
        #pragma unroll
        for (int j = 0; j < 4; ++j)
          if (px0 + j < 258) dst[j] = v[j];
      }
    }
  }
}

// ---------------- fused up2x (sep) + lrelu/clamp + down2x (sep), 8-row strips ----------------
// 320 threads; P2 parity-split into wave-uniform even/odd groups (no cndmask selects).
__global__ __launch_bounds__(320) void updown_kernel(
    const float* __restrict__ conv_out,
    const float* __restrict__ upf, const float* __restrict__ dnf,
    float* __restrict__ down2)
{
  __shared__ float Bp[26][268];   // up1 strip; cols [4,262) live, zero pad sides
  __shared__ float Dp[8][524];    // down1 strip (522 live cols + pad)
  const int strip = blockIdx.x, c = blockIdx.y, b = blockIdx.z;
  const int y0 = strip * 8;
  const int tid = threadIdx.x;
  float fu[12], fd[12];
  #pragma unroll
  for (int k = 0; k < 12; ++k) { fu[k] = upf[11-k] * 2.0f; fd[k] = dnf[11-k]; }
  if (tid < 260) {
    int r = tid / 10, pc = tid % 10;
    int col = (pc < 4) ? pc : (258 + pc);
    Bp[r][col] = 0.f;
  }
  const float* src = conv_out + ((size_t)(b*128 + c)*258)*258;

  // P1: vertical upsample, global -> LDS (one column per thread)
  if (tid < 258) {
    const int m = tid;
    float a[18];
    #pragma unroll
    for (int r = 0; r < 18; ++r) {
      int gy = y0 - 4 + r;
      a[r] = ((unsigned)gy < 258u) ? src[gy*258 + m] : 0.f;
    }
    #pragma unroll
    for (int v = 0; v < 26; ++v) {
      const int k0 = (v & 1) ? 0 : 1;
      float sacc = 0.f;
      #pragma unroll
      for (int j = 0; j < 6; ++j) {
        const int rl = (v + k0 + 2*j - 9)/2 + 4;   // compile-time, in [0,25]
        sacc += fu[k0 + 2*j] * a[rl];
      }
      Bp[v][m + 4] = sacc;
    }
  }
  __syncthreads();

  // P2: horizontal upsample + lrelu + vertical downsample, parity-specialized
  const float LA = 0.84852813742386f;   // 0.6*sqrt(2)
  const float LB = 0.56568542494924f;   // 0.4*sqrt(2)
  const bool evenp = tid < 131;
  const bool oddp  = (tid >= 160) && (tid < 290);
  if (evenp || oddp) {
    const int q = evenp ? (tid << 1) : (((tid - 160) << 1) + 1);
    const int qa = q & ~1;
    float cc0[26], cc1[26];
    if (evenp) {
      #pragma unroll
      for (int v = 0; v < 26; ++v) {
        float f[6];
        *(float2*)&f[0] = *(const float2*)&Bp[v][qa + 0];
        *(float2*)&f[2] = *(const float2*)&Bp[v][qa + 2];
        *(float2*)&f[4] = *(const float2*)&Bp[v][qa + 4];
        float c0 = fu[1]*f[0] + fu[3]*f[1] + fu[5]*f[2] + fu[7]*f[3] + fu[9]*f[4] + fu[11]*f[5];
        float c1 = fu[0]*f[0] + fu[2]*f[1] + fu[4]*f[2] + fu[6]*f[3] + fu[8]*f[4] + fu[10]*f[5];
        cc0[v] = fminf(fmaxf(LA*c0 + LB*__builtin_fabsf(c0), -256.f), 256.f);
        cc1[v] = fminf(fmaxf(LA*c1 + LB*__builtin_fabsf(c1), -256.f), 256.f);
      }
    } else {
      #pragma unroll
      for (int v = 0; v < 26; ++v) {
        float f[8];
        *(float2*)&f[0] = *(const float2*)&Bp[v][qa + 0];
        *(float2*)&f[2] = *(const float2*)&Bp[v][qa + 2];
        *(float2*)&f[4] = *(const float2*)&Bp[v][qa + 4];
        *(float2*)&f[6] = *(const float2*)&Bp[v][qa + 6];
        float c0 = fu[1]*f[1] + fu[3]*f[2] + fu[5]*f[3] + fu[7]*f[4] + fu[9]*f[5] + fu[11]*f[6];
        float c1 = fu[0]*f[1] + fu[2]*f[2] + fu[4]*f[3] + fu[6]*f[4] + fu[8]*f[5] + fu[10]*f[6];
        cc0[v] = fminf(fmaxf(LA*c0 + LB*__builtin_fabsf(c0), -256.f), 256.f);
        cc1[v] = fminf(fmaxf(LA*c1 + LB*__builtin_fabsf(c1), -256.f), 256.f);
      }
    }
    #pragma unroll
    for (int t = 0; t < 8; ++t) {
      float a0 = 0.f, a1 = 0.f;
      #pragma unroll
      for (int k = 0; k < 12; ++k) {
        a0 += fd[k]*cc0[2*t + k];
        a1 += fd[k]*cc1[2*t + k];
      }
      float2 pr; pr.x = a0; pr.y = a1;
      *(float2*)&Dp[t][2*q] = pr;
    }
  }
  __syncthreads();

  // P3: horizontal downsample, LDS -> global (8 rows x 32 threads/row)
  if (tid < 256) {
    const int ty = tid >> 5, xg = tid & 31;
    float* dstrow = down2 + ((size_t)(b*128 + c)*256 + (y0 + ty))*256;
    #pragma unroll
    for (int p = 0; p < 4; ++p) {
      const int pi = xg + 32*p;
      float fx[16];
      #pragma unroll
      for (int t = 0; t < 4; ++t)
        *(float4*)&fx[4*t] = *(const float4*)&Dp[ty][4*pi + 4*t];
      float o0 = 0.f, o1 = 0.f;
      #pragma unroll
      for (int k = 0; k < 12; ++k) {
        o0 += fd[k] * fx[k];
        o1 += fd[k] * fx[k + 2];
      }
      float2 st; st.x = o0; st.y = o1;
      *(float2*)&dstrow[2*pi] = st;
    }
  }
}

// ---------------- rgb: float4 per thread ----------------
__global__ __launch_bounds__(128) void rgb_kernel(
    const float* __restrict__ down2, const float* __restrict__ coef,
    const float* __restrict__ brgb, float* __restrict__ yout)
{
  __shared__ float cl[3][128];
  const int b = blockIdx.x >> 7;
  const int p4 = ((blockIdx.x & 127) << 7) + threadIdx.x;   // float4 idx 0..16383
  for (int e = threadIdx.x; e < 384; e += 128) cl[e >> 7][e & 127] = coef[b*384 + e];
  __syncthreads();
  f32x4 a0 = {0,0,0,0}, a1 = {0,0,0,0}, a2 = {0,0,0,0};
  const f32x4* dsrc = (const f32x4*)down2 + (size_t)b*2097152 + p4;
  #pragma unroll 4
  for (int i = 0; i < 128; ++i) {
    f32x4 v = dsrc[(size_t)i*16384];
    a0 += cl[0][i]*v; a1 += cl[1][i]*v; a2 += cl[2][i]*v;
  }
  f32x4* yo = (f32x4*)yout;
  const float b0 = brgb[0], b1 = brgb[1], b2 = brgb[2];
  #pragma unroll
  for (int j = 0; j < 4; ++j) {
    a0[j] = fminf(fmaxf(a0[j] + b0, -256.f), 256.f);
    a1[j] = fminf(fmaxf(a1[j] + b1, -256.f), 256.f);
    a2[j] = fminf(fmaxf(a2[j] + b2, -256.f), 256.f);
  }
  yo[(size_t)(b*3 + 0)*16384 + p4] = a0;
  yo[(size_t)(b*3 + 1)*16384 + p4] = a1;
  yo[(size_t)(b*3 + 2)*16384 + p4] = a2;
}

extern "C" void kernel_launch(void* const* d_in, const int* in_sizes, int n_in,
                              void* d_out, int out_size, void* d_ws, size_t ws_size,
                              hipStream_t stream) {
  const float* x      = (const float*)d_in[0];
  const float* w      = (const float*)d_in[1];
  const float* afw    = (const float*)d_in[2];
  const float* afb    = (const float*)d_in[3];
  const float* wfeat  = (const float*)d_in[4];
  const float* bfeat  = (const float*)d_in[5];
  const float* argbw  = (const float*)d_in[6];
  const float* argbb  = (const float*)d_in[7];
  const float* wrgb   = (const float*)d_in[8];
  const float* brgb   = (const float*)d_in[9];
  const float* upf    = (const float*)d_in[10];
  const float* dnf    = (const float*)d_in[11];
  const float* emaf   = (const float*)d_in[12];
  const float* emar   = (const float*)d_in[13];

  float* ws = (float*)d_ws;
  size_t off = 0;
  float* s_feat   = ws + off; off += 256;
  float* coef     = ws + off; off += 768;
  short* wfrag    = (short*)(ws + off); off += 147456;          // 294912 bf16
  float* conv_out = ws + off; off += (size_t)2*128*258*258;     // 17,040,384
  float* down2    = ws + off; off += (size_t)2*128*256*256;     // 16,777,216
  if (ws_size < off * sizeof(float)) return;
  float* yout = (float*)d_out;

  prep1_kernel<<<1, 256, 0, stream>>>(w, afw, afb, argbw, argbb, wrgb, emar,
                                      s_feat, coef);
  prep2_kernel<<<256, 128, 0, stream>>>(wfeat, s_feat, emaf, wfrag);
  conv_mfma_kernel<<<dim3(9, 65, 2), 256, 0, stream>>>(x, wfrag, bfeat, conv_out);
  updown_kernel<<<dim3(32, 128, 2), 320, 0, stream>>>(conv_out, upf, dnf, down2);
  rgb_kernel<<<256, 128, 0, stream>>>(down2, coef, brgb, yout);
}

// Round 10
// 255.518 us; speedup vs baseline: 1.3099x; 1.3099x over previous
//
#include <hip/hip_runtime.h>
#include <hip/hip_bf16.h>
#include <cstdint>

typedef __attribute__((ext_vector_type(8))) short bf16x8;
typedef __attribute__((ext_vector_type(4))) float f32x4;

__device__ inline uint16_t f2bf(float f) {
  uint32_t u = __float_as_uint(f);
  u += 0x7FFF + ((u >> 16) & 1);          // round-to-nearest-even
  return (uint16_t)(u >> 16);
}

// ---------------- prep1: s_feat (RMS-normalized), rgb coefs ----------------
__global__ __launch_bounds__(256) void prep1_kernel(
    const float* __restrict__ w,        // (2,512)
    const float* __restrict__ afw,      // (128,512)
    const float* __restrict__ afb,      // (128)
    const float* __restrict__ argbw,    // (128,512)
    const float* __restrict__ argbb,    // (128)
    const float* __restrict__ wrgb,     // (3,128)
    const float* __restrict__ ema_r,    // (1)
    float* __restrict__ s_feat_out,     // (2,128)
    float* __restrict__ coef_out)       // (2,3,128)
{
  __shared__ float sfeat_s[256];
  __shared__ float srgb_s[256];
  __shared__ float sred[256];
  const int tid = threadIdx.x, lane = tid & 63, wv = tid >> 6;
  const float wg = 0.04419417382415922f;    // 1/sqrt(512)
  #pragma unroll 2
  for (int p = wv; p < 256; p += 4) {
    const int bb = p >> 7, c = p & 127;
    float d1 = 0.f, d2 = 0.f;
    #pragma unroll
    for (int it = 0; it < 8; ++it) {
      const int k = lane + 64*it;
      const float wvv = w[bb*512 + k];
      d1 += wvv * afw[c*512 + k];
      d2 += wvv * argbw[c*512 + k];
    }
    #pragma unroll
    for (int off = 32; off; off >>= 1) {
      d1 += __shfl_xor(d1, off, 64);
      d2 += __shfl_xor(d2, off, 64);
    }
    if (lane == 0) {
      sfeat_s[p] = d1 * wg + afb[c];
      srgb_s[p]  = (d2 * wg + argbb[c]) * 0.08838834764831845f * rsqrtf(ema_r[0]);
    }
  }
  __syncthreads();
  const float sf = sfeat_s[tid];
  sred[tid] = sf * sf;
  __syncthreads();
  for (int off = 128; off > 0; off >>= 1) {
    if (tid < off) sred[tid] += sred[tid + off];
    __syncthreads();
  }
  const float snorm = rsqrtf(sred[0] * (1.0f/256.0f));
  s_feat_out[tid] = sf * snorm;
  for (int e = tid; e < 768; e += 256) {
    int bb = e / 384, o = (e % 384) / 128, i = e & 127;
    coef_out[e] = wrgb[o*128 + i] * srgb_s[bb*128 + i];
  }
}

// ---------------- prep2: wnscale (inline) + modulate + demod -> bf16 fragments ----------------
// wfrag layout: [b][kidx 0..35][mglob 0..7][lane 0..63][j 0..7]  (short/bf16)
__global__ __launch_bounds__(128) void prep2_kernel(
    const float* __restrict__ wfeat, const float* __restrict__ s_feat,
    const float* __restrict__ ema_f, short* __restrict__ wfrag)
{
  __shared__ float red[128];
  const int bo = blockIdx.x, b = bo >> 7, o = bo & 127;
  const int i = threadIdx.x;
  float wraw[9]; float ssr = 0.f;
  #pragma unroll
  for (int j = 0; j < 9; ++j) { wraw[j] = wfeat[(o*128 + i)*9 + j]; ssr += wraw[j]*wraw[j]; }
  red[i] = ssr; __syncthreads();
  for (int off = 64; off > 0; off >>= 1) { if (i < off) red[i] += red[i+off]; __syncthreads(); }
  const float wsc = rsqrtf(red[0] * (1.0f/1152.0f));
  const float sv = s_feat[b*128 + i];
  float wr[9]; float ss = 0.f;
  #pragma unroll
  for (int j = 0; j < 9; ++j) { wr[j] = wraw[j] * wsc * sv; ss += wr[j]*wr[j]; }
  __syncthreads();
  red[i] = ss; __syncthreads();
  for (int off = 64; off > 0; off >>= 1) { if (i < off) red[i] += red[i+off]; __syncthreads(); }
  const float d = rsqrtf(red[0] + 1e-8f) * rsqrtf(ema_f[0]);
  const int chunk = i >> 5;
  const int lane = (o & 15) | (((i >> 3) & 3) << 4);
  const int jj = i & 7;
  #pragma unroll
  for (int tap = 0; tap < 9; ++tap) {
    int kidx = chunk*9 + tap;
    size_t sidx = ((((size_t)b*36 + kidx)*8 + (o >> 4)) << 9) + (lane << 3) + jj;
    wfrag[sidx] = (short)f2bf(wr[tap] * d);
  }
}

// ---------------- conv via bf16 MFMA implicit GEMM ----------------
// (unchanged from round 9: 34-col LDS window, 3 blocks/CU, xf+wf 2-bank pipelined)
__global__ __launch_bounds__(256, 3) void conv_mfma_kernel(
    const float* __restrict__ x, const short* __restrict__ wfrag,
    const float* __restrict__ bias_feat, float* __restrict__ conv_out)
{
  __shared__ __align__(16) char xls[52224];
  __shared__ float bias_lds[128];
  const int tid = threadIdx.x;
  const int bx = blockIdx.x, by = blockIdx.y, b = blockIdx.z;
  const int x0 = bx * 32, y0 = by * 4;
  if (tid < 128) bias_lds[tid] = bias_feat[tid];

  const f32x4 f4z = {0.f, 0.f, 0.f, 0.f};
  const float* xb = x + (size_t)b * 8388608;

  // ---- stage x tile: 128 ic x 6 r x 34 c (fp32 -> bf16 pairs) ----
  {
    const int sl = tid & 7, pL = tid >> 3;              // sl: float4 slot, pL: ic-pair 0..31
    const int gxm = x0 + 4*sl;                          // main cols 2+4sl .. 5+4sl
    const bool xokm = (unsigned)gxm <= 252u;
    const int gxe = x0 - 2;
    #pragma unroll
    for (int r = 0; r < 6; ++r) {
      const int gy = y0 - 2 + r;
      const bool yok = (unsigned)gy < 256u;
      #pragma unroll
      for (int ph = 0; ph < 2; ++ph) {
        const int p = pL + 32*ph;                       // ic pair 0..63
        const float* s0 = xb + (size_t)(2*p)*65536 + gy*256 + gxm;
        const bool ok = yok && xokm;
        f32x4 v0 = ok ? *(const f32x4*)s0 : f4z;
        f32x4 v1 = ok ? *(const f32x4*)(s0 + 65536) : f4z;
        char* wb = xls + (size_t)(((r*16 + (p>>2))*34 + 2 + 4*sl)*16 + (p&3)*4);
        #pragma unroll
        for (int i2 = 0; i2 < 4; ++i2) {
          uint32_t pk = ((uint32_t)f2bf(v1[i2]) << 16) | f2bf(v0[i2]);
          *(uint32_t*)(wb + i2*16) = pk;
        }
        if (sl == 0) {                                  // edge cols 0,1 (gx = x0-2, x0-1)
          const bool eok = yok && (gxe >= 0);
          const float* e0 = xb + (size_t)(2*p)*65536 + gy*256 + gxe;
          float e00 = eok ? e0[0] : 0.f, e01 = eok ? e0[1] : 0.f;
          float e10 = eok ? e0[65536] : 0.f, e11 = eok ? e0[65537] : 0.f;
          char* eb = xls + (size_t)(((r*16 + (p>>2))*34)*16 + (p&3)*4);
          *(uint32_t*)eb        = ((uint32_t)f2bf(e10) << 16) | f2bf(e00);
          *(uint32_t*)(eb + 16) = ((uint32_t)f2bf(e11) << 16) | f2bf(e01);
        }
      }
    }
  }
  __syncthreads();

  // ---- K-loop: 36 kidx; xf (LDS) and wf (global) both 2-bank software-pipelined ----
  const int lane = tid & 63, wave = tid >> 6;
  const int wp = wave & 1, wo = wave >> 1;
  const int l15 = lane & 15, lq = lane >> 4;
  const short* wbase = wfrag + ((size_t)b*288 + wo*4)*512 + (size_t)lane*8;
  const int abase = ((wp*32 + lq)*34 + l15)*16;

  f32x4 acc[4][4] = {};
  bf16x8 wfA[4], wfB[4], xfA[4], xfB[4];

#define LDW(KI, WF) { const short* wp_ = wbase + (size_t)(KI)*4096;          \
    WF[0] = *(const bf16x8*)(wp_);       WF[1] = *(const bf16x8*)(wp_+512);  \
    WF[2] = *(const bf16x8*)(wp_+1024);  WF[3] = *(const bf16x8*)(wp_+1536); }

#define LDX(KI, XF) { const int ch_ = (KI)/9, tp_ = (KI)%9, ky_ = tp_/3, kx_ = tp_%3; \
    const int o00 = ((ky_*16 + ch_*4)*34 + kx_)*16;                           \
    const int o10 = o00 + 8704;                         /* +1 row = 16*34*16 */ \
    XF[0] = *(const bf16x8*)(xls + abase + o00);                              \
    XF[1] = *(const bf16x8*)(xls + abase + o00 + 256);                        \
    XF[2] = *(const bf16x8*)(xls + abase + o10);                              \
    XF[3] = *(const bf16x8*)(xls + abase + o10 + 256); }

#define MF(XF, WF) {                                                          \
    __builtin_amdgcn_s_setprio(1);                                            \
    acc[0][0] = __builtin_amdgcn_mfma_f32_16x16x32_bf16(XF[0], WF[0], acc[0][0], 0,0,0); \
    acc[0][1] = __builtin_amdgcn_mfma_f32_16x16x32_bf16(XF[0], WF[1], acc[0][1], 0,0,0); \
    acc[0][2] = __builtin_amdgcn_mfma_f32_16x16x32_bf16(XF[0], WF[2], acc[0][2], 0,0,0); \
    acc[0][3] = __builtin_amdgcn_mfma_f32_16x16x32_bf16(XF[0], WF[3], acc[0][3], 0,0,0); \
    acc[1][0] = __builtin_amdgcn_mfma_f32_16x16x32_bf16(XF[1], WF[0], acc[1][0], 0,0,0); \
    acc[1][1] = __builtin_amdgcn_mfma_f32_16x16x32_bf16(XF[1], WF[1], acc[1][1], 0,0,0); \
    acc[1][2] = __builtin_amdgcn_mfma_f32_16x16x32_bf16(XF[1], WF[2], acc[1][2], 0,0,0); \
    acc[1][3] = __builtin_amdgcn_mfma_f32_16x16x32_bf16(XF[1], WF[3], acc[1][3], 0,0,0); \
    acc[2][0] = __builtin_amdgcn_mfma_f32_16x16x32_bf16(XF[2], WF[0], acc[2][0], 0,0,0); \
    acc[2][1] = __builtin_amdgcn_mfma_f32_16x16x32_bf16(XF[2], WF[1], acc[2][1], 0,0,0); \
    acc[2][2] = __builtin_amdgcn_mfma_f32_16x16x32_bf16(XF[2], WF[2], acc[2][2], 0,0,0); \
    acc[2][3] = __builtin_amdgcn_mfma_f32_16x16x32_bf16(XF[2], WF[3], acc[2][3], 0,0,0); \
    acc[3][0] = __builtin_amdgcn_mfma_f32_16x16x32_bf16(XF[3], WF[0], acc[3][0], 0,0,0); \
    acc[3][1] = __builtin_amdgcn_mfma_f32_16x16x32_bf16(XF[3], WF[1], acc[3][1], 0,0,0); \
    acc[3][2] = __builtin_amdgcn_mfma_f32_16x16x32_bf16(XF[3], WF[2], acc[3][2], 0,0,0); \
    acc[3][3] = __builtin_amdgcn_mfma_f32_16x16x32_bf16(XF[3], WF[3], acc[3][3], 0,0,0); \
    __builtin_amdgcn_s_setprio(0); }

  LDX(0, xfA); LDW(0, wfA);
  LDX(1, xfB); LDW(1, wfB);
  #pragma unroll
  for (int kk = 0; kk < 36; kk += 2) {
    MF(xfA, wfA);
    if (kk + 2 < 36) { LDX(kk + 2, xfA); LDW(kk + 2, wfA); }
    MF(xfB, wfB);
    if (kk + 3 < 36) { LDX(kk + 3, xfB); LDW(kk + 3, wfB); }
  }
#undef LDW
#undef LDX
#undef MF

  // ---- epilogue: lane holds px = x0+(p&1)*16+lq*4+j (contig), oc = wo*64+o*16+l15 ----
  #pragma unroll
  for (int p = 0; p < 4; ++p) {
    const int py = y0 + wp*2 + (p>>1);
    if (py >= 258) continue;
    const int px0 = x0 + (p&1)*16 + lq*4;
    #pragma unroll
    for (int o = 0; o < 4; ++o) {
      const int oc = wo*64 + o*16 + l15;
      const float bz = bias_lds[oc];
      f32x4 v = acc[p][o];
      v[0] += bz; v[1] += bz; v[2] += bz; v[3] += bz;
      float* dst = conv_out + ((size_t)(b*128 + oc)*258 + py)*258 + px0;
      if (px0 <= 254) {
        *(f32x4*)dst = v;
      } else {
        #pragma unroll
        for (int j = 0; j < 4; ++j)
          if (px0 + j < 258) dst[j] = v[j];
      }
    }
  }
}

// ---------------- fused up2x (sep) + lrelu/clamp + down2x (sep), 8-row strips ----------------
// 320 threads; P2: select-free — both output parities read the SAME window Bp[v][q..q+5].
__global__ __launch_bounds__(320) void updown_kernel(
    const float* __restrict__ conv_out,
    const float* __restrict__ upf, const float* __restrict__ dnf,
    float* __restrict__ down2)
{
  __shared__ float Bp[26][268];   // up1 strip; cols [4,262) live, zero pad sides
  __shared__ float Dp[8][524];    // down1 strip (522 live cols + pad)
  const int strip = blockIdx.x, c = blockIdx.y, b = blockIdx.z;
  const int y0 = strip * 8;
  const int tid = threadIdx.x;
  float fu[12], fd[12];
  #pragma unroll
  for (int k = 0; k < 12; ++k) { fu[k] = upf[11-k] * 2.0f; fd[k] = dnf[11-k]; }
  if (tid < 260) {
    int r = tid / 10, pc = tid % 10;
    int col = (pc < 4) ? pc : (258 + pc);
    Bp[r][col] = 0.f;
  }
  const float* src = conv_out + ((size_t)(b*128 + c)*258)*258;

  // P1: vertical upsample, global -> LDS (one column per thread)
  if (tid < 258) {
    const int m = tid;
    float a[18];
    #pragma unroll
    for (int r = 0; r < 18; ++r) {
      int gy = y0 - 4 + r;
      a[r] = ((unsigned)gy < 258u) ? src[gy*258 + m] : 0.f;
    }
    #pragma unroll
    for (int v = 0; v < 26; ++v) {
      const int k0 = (v & 1) ? 0 : 1;
      float sacc = 0.f;
      #pragma unroll
      for (int j = 0; j < 6; ++j) {
        const int rl = (v + k0 + 2*j - 9)/2 + 4;   // compile-time, in [0,25]
        sacc += fu[k0 + 2*j] * a[rl];
      }
      Bp[v][m + 4] = sacc;
    }
  }
  __syncthreads();

  // P2: horizontal upsample + lrelu + vertical downsample (one q per thread, no selects)
  const float LA = 0.84852813742386f;   // 0.6*sqrt(2)
  const float LB = 0.56568542494924f;   // 0.4*sqrt(2)
  if (tid < 261) {
    const int q = tid;
    float cc0[26], cc1[26];
    #pragma unroll
    for (int v = 0; v < 26; ++v) {
      float f[6];
      #pragma unroll
      for (int j = 0; j < 6; ++j) f[j] = Bp[v][q + j];
      float c0 = fu[1]*f[0] + fu[3]*f[1] + fu[5]*f[2] + fu[7]*f[3] + fu[9]*f[4] + fu[11]*f[5];
      float c1 = fu[0]*f[0] + fu[2]*f[1] + fu[4]*f[2] + fu[6]*f[3] + fu[8]*f[4] + fu[10]*f[5];
      cc0[v] = fminf(fmaxf(LA*c0 + LB*__builtin_fabsf(c0), -256.f), 256.f);
      cc1[v] = fminf(fmaxf(LA*c1 + LB*__builtin_fabsf(c1), -256.f), 256.f);
    }
    #pragma unroll
    for (int t = 0; t < 8; ++t) {
      float a0 = 0.f, a1 = 0.f;
      #pragma unroll
      for (int k = 0; k < 12; ++k) {
        a0 += fd[k]*cc0[2*t + k];
        a1 += fd[k]*cc1[2*t + k];
      }
      float2 pr; pr.x = a0; pr.y = a1;
      *(float2*)&Dp[t][2*q] = pr;
    }
  }
  __syncthreads();

  // P3: horizontal downsample, LDS -> global (8 rows x 32 threads/row)
  if (tid < 256) {
    const int ty = tid >> 5, xg = tid & 31;
    float* dstrow = down2 + ((size_t)(b*128 + c)*256 + (y0 + ty))*256;
    #pragma unroll
    for (int p = 0; p < 4; ++p) {
      const int pi = xg + 32*p;
      float fx[16];
      #pragma unroll
      for (int t = 0; t < 4; ++t)
        *(float4*)&fx[4*t] = *(const float4*)&Dp[ty][4*pi + 4*t];
      float o0 = 0.f, o1 = 0.f;
      #pragma unroll
      for (int k = 0; k < 12; ++k) {
        o0 += fd[k] * fx[k];
        o1 += fd[k] * fx[k + 2];
      }
      float2 st; st.x = o0; st.y = o1;
      *(float2*)&dstrow[2*pi] = st;
    }
  }
}

// ---------------- rgb: float4 per thread ----------------
__global__ __launch_bounds__(128) void rgb_kernel(
    const float* __restrict__ down2, const float* __restrict__ coef,
    const float* __restrict__ brgb, float* __restrict__ yout)
{
  __shared__ float cl[3][128];
  const int b = blockIdx.x >> 7;
  const int p4 = ((blockIdx.x & 127) << 7) + threadIdx.x;   // float4 idx 0..16383
  for (int e = threadIdx.x; e < 384; e += 128) cl[e >> 7][e & 127] = coef[b*384 + e];
  __syncthreads();
  f32x4 a0 = {0,0,0,0}, a1 = {0,0,0,0}, a2 = {0,0,0,0};
  const f32x4* dsrc = (const f32x4*)down2 + (size_t)b*2097152 + p4;
  #pragma unroll 4
  for (int i = 0; i < 128; ++i) {
    f32x4 v = dsrc[(size_t)i*16384];
    a0 += cl[0][i]*v; a1 += cl[1][i]*v; a2 += cl[2][i]*v;
  }
  f32x4* yo = (f32x4*)yout;
  const float b0 = brgb[0], b1 = brgb[1], b2 = brgb[2];
  #pragma unroll
  for (int j = 0; j < 4; ++j) {
    a0[j] = fminf(fmaxf(a0[j] + b0, -256.f), 256.f);
    a1[j] = fminf(fmaxf(a1[j] + b1, -256.f), 256.f);
    a2[j] = fminf(fmaxf(a2[j] + b2, -256.f), 256.f);
  }
  yo[(size_t)(b*3 + 0)*16384 + p4] = a0;
  yo[(size_t)(b*3 + 1)*16384 + p4] = a1;
  yo[(size_t)(b*3 + 2)*16384 + p4] = a2;
}

extern "C" void kernel_launch(void* const* d_in, const int* in_sizes, int n_in,
                              void* d_out, int out_size, void* d_ws, size_t ws_size,
                              hipStream_t stream) {
  const float* x      = (const float*)d_in[0];
  const float* w      = (const float*)d_in[1];
  const float* afw    = (const float*)d_in[2];
  const float* afb    = (const float*)d_in[3];
  const float* wfeat  = (const float*)d_in[4];
  const float* bfeat  = (const float*)d_in[5];
  const float* argbw  = (const float*)d_in[6];
  const float* argbb  = (const float*)d_in[7];
  const float* wrgb   = (const float*)d_in[8];
  const float* brgb   = (const float*)d_in[9];
  const float* upf    = (const float*)d_in[10];
  const float* dnf    = (const float*)d_in[11];
  const float* emaf   = (const float*)d_in[12];
  const float* emar   = (const float*)d_in[13];

  float* ws = (float*)d_ws;
  size_t off = 0;
  float* s_feat   = ws + off; off += 256;
  float* coef     = ws + off; off += 768;
  short* wfrag    = (short*)(ws + off); off += 147456;          // 294912 bf16
  float* conv_out = ws + off; off += (size_t)2*128*258*258;     // 17,040,384
  float* down2    = ws + off; off += (size_t)2*128*256*256;     // 16,777,216
  if (ws_size < off * sizeof(float)) return;
  float* yout = (float*)d_out;

  prep1_kernel<<<1, 256, 0, stream>>>(w, afw, afb, argbw, argbb, wrgb, emar,
                                      s_feat, coef);
  prep2_kernel<<<256, 128, 0, stream>>>(wfeat, s_feat, emaf, wfrag);
  conv_mfma_kernel<<<dim3(9, 65, 2), 256, 0, stream>>>(x, wfrag, bfeat, conv_out);
  updown_kernel<<<dim3(32, 128, 2), 320, 0, stream>>>(conv_out, upf, dnf, down2);
  rgb_kernel<<<256, 128, 0, stream>>>(down2, coef, brgb, yout);
}

// Round 11
// 228.858 us; speedup vs baseline: 1.4625x; 1.1165x over previous
//
#include <hip/hip_runtime.h>
#include <hip/hip_bf16.h>
#include <cstdint>

typedef __attribute__((ext_vector_type(8))) short bf16x8;
typedef __attribute__((ext_vector_type(4))) float f32x4;
typedef __attribute__((ext_vector_type(2))) float f32x2;

__device__ inline uint16_t f2bf(float f) {
  uint32_t u = __float_as_uint(f);
  u += 0x7FFF + ((u >> 16) & 1);          // round-to-nearest-even
  return (uint16_t)(u >> 16);
}

// ---------------- prep1: s_feat (RMS-normalized), rgb coefs ----------------
__global__ __launch_bounds__(256) void prep1_kernel(
    const float* __restrict__ w,        // (2,512)
    const float* __restrict__ afw,      // (128,512)
    const float* __restrict__ afb,      // (128)
    const float* __restrict__ argbw,    // (128,512)
    const float* __restrict__ argbb,    // (128)
    const float* __restrict__ wrgb,     // (3,128)
    const float* __restrict__ ema_r,    // (1)
    float* __restrict__ s_feat_out,     // (2,128)
    float* __restrict__ coef_out)       // (2,3,128)
{
  __shared__ float sfeat_s[256];
  __shared__ float srgb_s[256];
  __shared__ float sred[256];
  const int tid = threadIdx.x, lane = tid & 63, wv = tid >> 6;
  const float wg = 0.04419417382415922f;    // 1/sqrt(512)
  #pragma unroll 2
  for (int p = wv; p < 256; p += 4) {
    const int bb = p >> 7, c = p & 127;
    float d1 = 0.f, d2 = 0.f;
    #pragma unroll
    for (int it = 0; it < 8; ++it) {
      const int k = lane + 64*it;
      const float wvv = w[bb*512 + k];
      d1 += wvv * afw[c*512 + k];
      d2 += wvv * argbw[c*512 + k];
    }
    #pragma unroll
    for (int off = 32; off; off >>= 1) {
      d1 += __shfl_xor(d1, off, 64);
      d2 += __shfl_xor(d2, off, 64);
    }
    if (lane == 0) {
      sfeat_s[p] = d1 * wg + afb[c];
      srgb_s[p]  = (d2 * wg + argbb[c]) * 0.08838834764831845f * rsqrtf(ema_r[0]);
    }
  }
  __syncthreads();
  const float sf = sfeat_s[tid];
  sred[tid] = sf * sf;
  __syncthreads();
  for (int off = 128; off > 0; off >>= 1) {
    if (tid < off) sred[tid] += sred[tid + off];
    __syncthreads();
  }
  const float snorm = rsqrtf(sred[0] * (1.0f/256.0f));
  s_feat_out[tid] = sf * snorm;
  for (int e = tid; e < 768; e += 256) {
    int bb = e / 384, o = (e % 384) / 128, i = e & 127;
    coef_out[e] = wrgb[o*128 + i] * srgb_s[bb*128 + i];
  }
}

// ---------------- prep2: wnscale (inline) + modulate + demod -> bf16 fragments ----------------
// wfrag layout: [b][kidx 0..35][mglob 0..7][lane 0..63][j 0..7]  (short/bf16)
__global__ __launch_bounds__(128) void prep2_kernel(
    const float* __restrict__ wfeat, const float* __restrict__ s_feat,
    const float* __restrict__ ema_f, short* __restrict__ wfrag)
{
  __shared__ float red[128];
  const int bo = blockIdx.x, b = bo >> 7, o = bo & 127;
  const int i = threadIdx.x;
  float wraw[9]; float ssr = 0.f;
  #pragma unroll
  for (int j = 0; j < 9; ++j) { wraw[j] = wfeat[(o*128 + i)*9 + j]; ssr += wraw[j]*wraw[j]; }
  red[i] = ssr; __syncthreads();
  for (int off = 64; off > 0; off >>= 1) { if (i < off) red[i] += red[i+off]; __syncthreads(); }
  const float wsc = rsqrtf(red[0] * (1.0f/1152.0f));
  const float sv = s_feat[b*128 + i];
  float wr[9]; float ss = 0.f;
  #pragma unroll
  for (int j = 0; j < 9; ++j) { wr[j] = wraw[j] * wsc * sv; ss += wr[j]*wr[j]; }
  __syncthreads();
  red[i] = ss; __syncthreads();
  for (int off = 64; off > 0; off >>= 1) { if (i < off) red[i] += red[i+off]; __syncthreads(); }
  const float d = rsqrtf(red[0] + 1e-8f) * rsqrtf(ema_f[0]);
  const int chunk = i >> 5;
  const int lane = (o & 15) | (((i >> 3) & 3) << 4);
  const int jj = i & 7;
  #pragma unroll
  for (int tap = 0; tap < 9; ++tap) {
    int kidx = chunk*9 + tap;
    size_t sidx = ((((size_t)b*36 + kidx)*8 + (o >> 4)) << 9) + (lane << 3) + jj;
    wfrag[sidx] = (short)f2bf(wr[tap] * d);
  }
}

// ---------------- conv via bf16 MFMA implicit GEMM ----------------
// (unchanged from round 9: 34-col LDS window, 3 blocks/CU, xf+wf 2-bank pipelined)
__global__ __launch_bounds__(256, 3) void conv_mfma_kernel(
    const float* __restrict__ x, const short* __restrict__ wfrag,
    const float* __restrict__ bias_feat, float* __restrict__ conv_out)
{
  __shared__ __align__(16) char xls[52224];
  __shared__ float bias_lds[128];
  const int tid = threadIdx.x;
  const int bx = blockIdx.x, by = blockIdx.y, b = blockIdx.z;
  const int x0 = bx * 32, y0 = by * 4;
  if (tid < 128) bias_lds[tid] = bias_feat[tid];

  const f32x4 f4z = {0.f, 0.f, 0.f, 0.f};
  const float* xb = x + (size_t)b * 8388608;

  // ---- stage x tile: 128 ic x 6 r x 34 c (fp32 -> bf16 pairs) ----
  {
    const int sl = tid & 7, pL = tid >> 3;              // sl: float4 slot, pL: ic-pair 0..31
    const int gxm = x0 + 4*sl;                          // main cols 2+4sl .. 5+4sl
    const bool xokm = (unsigned)gxm <= 252u;
    const int gxe = x0 - 2;
    #pragma unroll
    for (int r = 0; r < 6; ++r) {
      const int gy = y0 - 2 + r;
      const bool yok = (unsigned)gy < 256u;
      #pragma unroll
      for (int ph = 0; ph < 2; ++ph) {
        const int p = pL + 32*ph;                       // ic pair 0..63
        const float* s0 = xb + (size_t)(2*p)*65536 + gy*256 + gxm;
        const bool ok = yok && xokm;
        f32x4 v0 = ok ? *(const f32x4*)s0 : f4z;
        f32x4 v1 = ok ? *(const f32x4*)(s0 + 65536) : f4z;
        char* wb = xls + (size_t)(((r*16 + (p>>2))*34 + 2 + 4*sl)*16 + (p&3)*4);
        #pragma unroll
        for (int i2 = 0; i2 < 4; ++i2) {
          uint32_t pk = ((uint32_t)f2bf(v1[i2]) << 16) | f2bf(v0[i2]);
          *(uint32_t*)(wb + i2*16) = pk;
        }
        if (sl == 0) {                                  // edge cols 0,1 (gx = x0-2, x0-1)
          const bool eok = yok && (gxe >= 0);
          const float* e0 = xb + (size_t)(2*p)*65536 + gy*256 + gxe;
          float e00 = eok ? e0[0] : 0.f, e01 = eok ? e0[1] : 0.f;
          float e10 = eok ? e0[65536] : 0.f, e11 = eok ? e0[65537] : 0.f;
          char* eb = xls + (size_t)(((r*16 + (p>>2))*34)*16 + (p&3)*4);
          *(uint32_t*)eb        = ((uint32_t)f2bf(e10) << 16) | f2bf(e00);
          *(uint32_t*)(eb + 16) = ((uint32_t)f2bf(e11) << 16) | f2bf(e01);
        }
      }
    }
  }
  __syncthreads();

  // ---- K-loop: 36 kidx; xf (LDS) and wf (global) both 2-bank software-pipelined ----
  const int lane = tid & 63, wave = tid >> 6;
  const int wp = wave & 1, wo = wave >> 1;
  const int l15 = lane & 15, lq = lane >> 4;
  const short* wbase = wfrag + ((size_t)b*288 + wo*4)*512 + (size_t)lane*8;
  const int abase = ((wp*32 + lq)*34 + l15)*16;

  f32x4 acc[4][4] = {};
  bf16x8 wfA[4], wfB[4], xfA[4], xfB[4];

#define LDW(KI, WF) { const short* wp_ = wbase + (size_t)(KI)*4096;          \
    WF[0] = *(const bf16x8*)(wp_);       WF[1] = *(const bf16x8*)(wp_+512);  \
    WF[2] = *(const bf16x8*)(wp_+1024);  WF[3] = *(const bf16x8*)(wp_+1536); }

#define LDX(KI, XF) { const int ch_ = (KI)/9, tp_ = (KI)%9, ky_ = tp_/3, kx_ = tp_%3; \
    const int o00 = ((ky_*16 + ch_*4)*34 + kx_)*16;                           \
    const int o10 = o00 + 8704;                         /* +1 row = 16*34*16 */ \
    XF[0] = *(const bf16x8*)(xls + abase + o00);                              \
    XF[1] = *(const bf16x8*)(xls + abase + o00 + 256);                        \
    XF[2] = *(const bf16x8*)(xls + abase + o10);                              \
    XF[3] = *(const bf16x8*)(xls + abase + o10 + 256); }

#define MF(XF, WF) {                                                          \
    __builtin_amdgcn_s_setprio(1);                                            \
    acc[0][0] = __builtin_amdgcn_mfma_f32_16x16x32_bf16(XF[0], WF[0], acc[0][0], 0,0,0); \
    acc[0][1] = __builtin_amdgcn_mfma_f32_16x16x32_bf16(XF[0], WF[1], acc[0][1], 0,0,0); \
    acc[0][2] = __builtin_amdgcn_mfma_f32_16x16x32_bf16(XF[0], WF[2], acc[0][2], 0,0,0); \
    acc[0][3] = __builtin_amdgcn_mfma_f32_16x16x32_bf16(XF[0], WF[3], acc[0][3], 0,0,0); \
    acc[1][0] = __builtin_amdgcn_mfma_f32_16x16x32_bf16(XF[1], WF[0], acc[1][0], 0,0,0); \
    acc[1][1] = __builtin_amdgcn_mfma_f32_16x16x32_bf16(XF[1], WF[1], acc[1][1], 0,0,0); \
    acc[1][2] = __builtin_amdgcn_mfma_f32_16x16x32_bf16(XF[1], WF[2], acc[1][2], 0,0,0); \
    acc[1][3] = __builtin_amdgcn_mfma_f32_16x16x32_bf16(XF[1], WF[3], acc[1][3], 0,0,0); \
    acc[2][0] = __builtin_amdgcn_mfma_f32_16x16x32_bf16(XF[2], WF[0], acc[2][0], 0,0,0); \
    acc[2][1] = __builtin_amdgcn_mfma_f32_16x16x32_bf16(XF[2], WF[1], acc[2][1], 0,0,0); \
    acc[2][2] = __builtin_amdgcn_mfma_f32_16x16x32_bf16(XF[2], WF[2], acc[2][2], 0,0,0); \
    acc[2][3] = __builtin_amdgcn_mfma_f32_16x16x32_bf16(XF[2], WF[3], acc[2][3], 0,0,0); \
    acc[3][0] = __builtin_amdgcn_mfma_f32_16x16x32_bf16(XF[3], WF[0], acc[3][0], 0,0,0); \
    acc[3][1] = __builtin_amdgcn_mfma_f32_16x16x32_bf16(XF[3], WF[1], acc[3][1], 0,0,0); \
    acc[3][2] = __builtin_amdgcn_mfma_f32_16x16x32_bf16(XF[3], WF[2], acc[3][2], 0,0,0); \
    acc[3][3] = __builtin_amdgcn_mfma_f32_16x16x32_bf16(XF[3], WF[3], acc[3][3], 0,0,0); \
    __builtin_amdgcn_s_setprio(0); }

  LDX(0, xfA); LDW(0, wfA);
  LDX(1, xfB); LDW(1, wfB);
  #pragma unroll
  for (int kk = 0; kk < 36; kk += 2) {
    MF(xfA, wfA);
    if (kk + 2 < 36) { LDX(kk + 2, xfA); LDW(kk + 2, wfA); }
    MF(xfB, wfB);
    if (kk + 3 < 36) { LDX(kk + 3, xfB); LDW(kk + 3, wfB); }
  }
#undef LDW
#undef LDX
#undef MF

  // ---- epilogue: lane holds px = x0+(p&1)*16+lq*4+j (contig), oc = wo*64+o*16+l15 ----
  #pragma unroll
  for (int p = 0; p < 4; ++p) {
    const int py = y0 + wp*2 + (p>>1);
    if (py >= 258) continue;
    const int px0 = x0 + (p&1)*16 + lq*4;
    #pragma unroll
    for (int o = 0; o < 4; ++o) {
      const int oc = wo*64 + o*16 + l15;
      const float bz = bias_lds[oc];
      f32x4 v = acc[p][o];
      v[0] += bz; v[1] += bz; v[2] += bz; v[3] += bz;
      float* dst = conv_out + ((size_t)(b*128 + oc)*258 + py)*258 + px0;
      if (px0 <= 254) {
        *(f32x4*)dst = v;
      } else {
        #pragma unroll
        for (int j = 0; j < 4; ++j)
          if (px0 + j < 258) dst[j] = v[j];
      }
    }
  }
}

// ---------------- fused up2x (sep) + lrelu/clamp + down2x (sep), 8-row strips ----------------
// 256 threads (r5 structure). Packed-fp32 P1 (row pairs) and P2 (parity pair) — all
// tap arrays compile-time-indexed (fup[j] = (fu[2j+1], fu[2j]) serves BOTH phases).
__global__ __launch_bounds__(256) void updown_kernel(
    const float* __restrict__ conv_out,
    const float* __restrict__ upf, const float* __restrict__ dnf,
    float* __restrict__ down2)
{
  __shared__ float Bp[26][268];   // up1 strip; cols [4,262) live, zero pad sides
  __shared__ float Dp[8][524];    // down1 strip (522 live cols + pad)
  const int strip = blockIdx.x, c = blockIdx.y, b = blockIdx.z;
  const int y0 = strip * 8;
  const int tid = threadIdx.x;
  float fu[12], fd[12];
  #pragma unroll
  for (int k = 0; k < 12; ++k) { fu[k] = upf[11-k] * 2.0f; fd[k] = dnf[11-k]; }
  f32x2 fup[6];                   // (even-output tap, odd-output tap)
  #pragma unroll
  for (int j = 0; j < 6; ++j) fup[j] = (f32x2){fu[2*j+1], fu[2*j]};
  for (int e = tid; e < 260; e += 256) {
    int r = e / 10, pc = e % 10;
    int col = (pc < 4) ? pc : (258 + pc);
    Bp[r][col] = 0.f;
  }
  const float* src = conv_out + ((size_t)(b*128 + c)*258)*258;

  // P1: vertical upsample, packed row-pairs (v=2m, 2m+1 share inputs a[mp+j])
  #pragma unroll 1
  for (int m = tid; m < 258; m += 256) {
    float a[18];
    #pragma unroll
    for (int r = 0; r < 18; ++r) {
      int gy = y0 - 4 + r;
      a[r] = ((unsigned)gy < 258u) ? src[gy*258 + m] : 0.f;
    }
    #pragma unroll
    for (int mp = 0; mp < 13; ++mp) {
      f32x2 s2 = {0.f, 0.f};
      #pragma unroll
      for (int j = 0; j < 6; ++j) s2 += fup[j] * a[mp + j];
      Bp[2*mp][m + 4]     = s2[0];
      Bp[2*mp + 1][m + 4] = s2[1];
    }
  }
  __syncthreads();

  // P2: horizontal upsample (packed parity pair, shared window Bp[v][q..q+5])
  //     + lrelu(|x|) + packed vertical downsample
  const float LA = 0.84852813742386f;   // 0.6*sqrt(2)
  const float LB = 0.56568542494924f;   // 0.4*sqrt(2)
  #pragma unroll 1
  for (int q = tid; q < 261; q += 256) {
    f32x2 cc[26];
    #pragma unroll
    for (int v = 0; v < 26; ++v) {
      f32x2 c2 = {0.f, 0.f};
      #pragma unroll
      for (int j = 0; j < 6; ++j) c2 += fup[j] * Bp[v][q + j];
      f32x2 ab;
      ab[0] = __builtin_fabsf(c2[0]);
      ab[1] = __builtin_fabsf(c2[1]);
      c2 = LA*c2 + LB*ab;
      c2[0] = fminf(fmaxf(c2[0], -256.f), 256.f);
      c2[1] = fminf(fmaxf(c2[1], -256.f), 256.f);
      cc[v] = c2;
    }
    #pragma unroll
    for (int t = 0; t < 8; ++t) {
      f32x2 d = {0.f, 0.f};
      #pragma unroll
      for (int k = 0; k < 12; ++k) d += fd[k] * cc[2*t + k];
      *(f32x2*)&Dp[t][2*q] = d;
    }
  }
  __syncthreads();

  // P3: horizontal downsample, LDS -> global (8 rows x 32 threads/row)
  {
    const int ty = tid >> 5, xg = tid & 31;
    float* dstrow = down2 + ((size_t)(b*128 + c)*256 + (y0 + ty))*256;
    #pragma unroll
    for (int p = 0; p < 4; ++p) {
      const int pi = xg + 32*p;
      float fx[16];
      #pragma unroll
      for (int t = 0; t < 4; ++t)
        *(float4*)&fx[4*t] = *(const float4*)&Dp[ty][4*pi + 4*t];
      float o0 = 0.f, o1 = 0.f;
      #pragma unroll
      for (int k = 0; k < 12; ++k) {
        o0 += fd[k] * fx[k];
        o1 += fd[k] * fx[k + 2];
      }
      float2 st; st.x = o0; st.y = o1;
      *(float2*)&dstrow[2*pi] = st;
    }
  }
}

// ---------------- rgb: float4 per thread ----------------
__global__ __launch_bounds__(128) void rgb_kernel(
    const float* __restrict__ down2, const float* __restrict__ coef,
    const float* __restrict__ brgb, float* __restrict__ yout)
{
  __shared__ float cl[3][128];
  const int b = blockIdx.x >> 7;
  const int p4 = ((blockIdx.x & 127) << 7) + threadIdx.x;   // float4 idx 0..16383
  for (int e = threadIdx.x; e < 384; e += 128) cl[e >> 7][e & 127] = coef[b*384 + e];
  __syncthreads();
  f32x4 a0 = {0,0,0,0}, a1 = {0,0,0,0}, a2 = {0,0,0,0};
  const f32x4* dsrc = (const f32x4*)down2 + (size_t)b*2097152 + p4;
  #pragma unroll 4
  for (int i = 0; i < 128; ++i) {
    f32x4 v = dsrc[(size_t)i*16384];
    a0 += cl[0][i]*v; a1 += cl[1][i]*v; a2 += cl[2][i]*v;
  }
  f32x4* yo = (f32x4*)yout;
  const float b0 = brgb[0], b1 = brgb[1], b2 = brgb[2];
  #pragma unroll
  for (int j = 0; j < 4; ++j) {
    a0[j] = fminf(fmaxf(a0[j] + b0, -256.f), 256.f);
    a1[j] = fminf(fmaxf(a1[j] + b1, -256.f), 256.f);
    a2[j] = fminf(fmaxf(a2[j] + b2, -256.f), 256.f);
  }
  yo[(size_t)(b*3 + 0)*16384 + p4] = a0;
  yo[(size_t)(b*3 + 1)*16384 + p4] = a1;
  yo[(size_t)(b*3 + 2)*16384 + p4] = a2;
}

extern "C" void kernel_launch(void* const* d_in, const int* in_sizes, int n_in,
                              void* d_out, int out_size, void* d_ws, size_t ws_size,
                              hipStream_t stream) {
  const float* x      = (const float*)d_in[0];
  const float* w      = (const float*)d_in[1];
  const float* afw    = (const float*)d_in[2];
  const float* afb    = (const float*)d_in[3];
  const float* wfeat  = (const float*)d_in[4];
  const float* bfeat  = (const float*)d_in[5];
  const float* argbw  = (const float*)d_in[6];
  const float* argbb  = (const float*)d_in[7];
  const float* wrgb   = (const float*)d_in[8];
  const float* brgb   = (const float*)d_in[9];
  const float* upf    = (const float*)d_in[10];
  const float* dnf    = (const float*)d_in[11];
  const float* emaf   = (const float*)d_in[12];
  const float* emar   = (const float*)d_in[13];

  float* ws = (float*)d_ws;
  size_t off = 0;
  float* s_feat   = ws + off; off += 256;
  float* coef     = ws + off; off += 768;
  short* wfrag    = (short*)(ws + off); off += 147456;          // 294912 bf16
  float* conv_out = ws + off; off += (size_t)2*128*258*258;     // 17,040,384
  float* down2    = ws + off; off += (size_t)2*128*256*256;     // 16,777,216
  if (ws_size < off * sizeof(float)) return;
  float* yout = (float*)d_out;

  prep1_kernel<<<1, 256, 0, stream>>>(w, afw, afb, argbw, argbb, wrgb, emar,
                                      s_feat, coef);
  prep2_kernel<<<256, 128, 0, stream>>>(wfeat, s_feat, emaf, wfrag);
  conv_mfma_kernel<<<dim3(9, 65, 2), 256, 0, stream>>>(x, wfrag, bfeat, conv_out);
  updown_kernel<<<dim3(32, 128, 2), 256, 0, stream>>>(conv_out, upf, dnf, down2);
  rgb_kernel<<<256, 128, 0, stream>>>(down2, coef, brgb, yout);
}

// Round 12
// 228.699 us; speedup vs baseline: 1.4635x; 1.0007x over previous
//
#include <hip/hip_runtime.h>
#include <hip/hip_bf16.h>
#include <cstdint>

typedef __attribute__((ext_vector_type(8))) short bf16x8;
typedef __attribute__((ext_vector_type(4))) float f32x4;
typedef __attribute__((ext_vector_type(2))) float f32x2;

__device__ inline uint16_t f2bf(float f) {
  uint32_t u = __float_as_uint(f);
  u += 0x7FFF + ((u >> 16) & 1);          // round-to-nearest-even
  return (uint16_t)(u >> 16);
}

// ---------------- prep1: s_feat (RMS-normalized), rgb coefs ----------------
__global__ __launch_bounds__(256) void prep1_kernel(
    const float* __restrict__ w,        // (2,512)
    const float* __restrict__ afw,      // (128,512)
    const float* __restrict__ afb,      // (128)
    const float* __restrict__ argbw,    // (128,512)
    const float* __restrict__ argbb,    // (128)
    const float* __restrict__ wrgb,     // (3,128)
    const float* __restrict__ ema_r,    // (1)
    float* __restrict__ s_feat_out,     // (2,128)
    float* __restrict__ coef_out)       // (2,3,128)
{
  __shared__ float sfeat_s[256];
  __shared__ float srgb_s[256];
  __shared__ float sred[256];
  const int tid = threadIdx.x, lane = tid & 63, wv = tid >> 6;
  const float wg = 0.04419417382415922f;    // 1/sqrt(512)
  #pragma unroll 2
  for (int p = wv; p < 256; p += 4) {
    const int bb = p >> 7, c = p & 127;
    float d1 = 0.f, d2 = 0.f;
    #pragma unroll
    for (int it = 0; it < 8; ++it) {
      const int k = lane + 64*it;
      const float wvv = w[bb*512 + k];
      d1 += wvv * afw[c*512 + k];
      d2 += wvv * argbw[c*512 + k];
    }
    #pragma unroll
    for (int off = 32; off; off >>= 1) {
      d1 += __shfl_xor(d1, off, 64);
      d2 += __shfl_xor(d2, off, 64);
    }
    if (lane == 0) {
      sfeat_s[p] = d1 * wg + afb[c];
      srgb_s[p]  = (d2 * wg + argbb[c]) * 0.08838834764831845f * rsqrtf(ema_r[0]);
    }
  }
  __syncthreads();
  const float sf = sfeat_s[tid];
  sred[tid] = sf * sf;
  __syncthreads();
  for (int off = 128; off > 0; off >>= 1) {
    if (tid < off) sred[tid] += sred[tid + off];
    __syncthreads();
  }
  const float snorm = rsqrtf(sred[0] * (1.0f/256.0f));
  s_feat_out[tid] = sf * snorm;
  for (int e = tid; e < 768; e += 256) {
    int bb = e / 384, o = (e % 384) / 128, i = e & 127;
    coef_out[e] = wrgb[o*128 + i] * srgb_s[bb*128 + i];
  }
}

// ---------------- prep2: wnscale (inline) + modulate + demod -> bf16 fragments ----------------
// wfrag layout: [b][kidx 0..35][mglob 0..7][lane 0..63][j 0..7]  (short/bf16)
__global__ __launch_bounds__(128) void prep2_kernel(
    const float* __restrict__ wfeat, const float* __restrict__ s_feat,
    const float* __restrict__ ema_f, short* __restrict__ wfrag)
{
  __shared__ float red[128];
  const int bo = blockIdx.x, b = bo >> 7, o = bo & 127;
  const int i = threadIdx.x;
  float wraw[9]; float ssr = 0.f;
  #pragma unroll
  for (int j = 0; j < 9; ++j) { wraw[j] = wfeat[(o*128 + i)*9 + j]; ssr += wraw[j]*wraw[j]; }
  red[i] = ssr; __syncthreads();
  for (int off = 64; off > 0; off >>= 1) { if (i < off) red[i] += red[i+off]; __syncthreads(); }
  const float wsc = rsqrtf(red[0] * (1.0f/1152.0f));
  const float sv = s_feat[b*128 + i];
  float wr[9]; float ss = 0.f;
  #pragma unroll
  for (int j = 0; j < 9; ++j) { wr[j] = wraw[j] * wsc * sv; ss += wr[j]*wr[j]; }
  __syncthreads();
  red[i] = ss; __syncthreads();
  for (int off = 64; off > 0; off >>= 1) { if (i < off) red[i] += red[i+off]; __syncthreads(); }
  const float d = rsqrtf(red[0] + 1e-8f) * rsqrtf(ema_f[0]);
  const int chunk = i >> 5;
  const int lane = (o & 15) | (((i >> 3) & 3) << 4);
  const int jj = i & 7;
  #pragma unroll
  for (int tap = 0; tap < 9; ++tap) {
    int kidx = chunk*9 + tap;
    size_t sidx = ((((size_t)b*36 + kidx)*8 + (o >> 4)) << 9) + (lane << 3) + jj;
    wfrag[sidx] = (short)f2bf(wr[tap] * d);
  }
}

// ---------------- conv via bf16 MFMA implicit GEMM ----------------
// 34-col LDS window, 3 blocks/CU; wf (global/L2) pipelined 3-deep (covers ~2 MF
// clusters ~200cyc = L2 latency); xf loaded JIT inside cluster (LDS, lgkm-overlapped).
__global__ __launch_bounds__(256, 3) void conv_mfma_kernel(
    const float* __restrict__ x, const short* __restrict__ wfrag,
    const float* __restrict__ bias_feat, float* __restrict__ conv_out)
{
  __shared__ __align__(16) char xls[52224];
  __shared__ float bias_lds[128];
  const int tid = threadIdx.x;
  const int bx = blockIdx.x, by = blockIdx.y, b = blockIdx.z;
  const int x0 = bx * 32, y0 = by * 4;
  if (tid < 128) bias_lds[tid] = bias_feat[tid];

  const f32x4 f4z = {0.f, 0.f, 0.f, 0.f};
  const float* xb = x + (size_t)b * 8388608;

  // ---- stage x tile: 128 ic x 6 r x 34 c (fp32 -> bf16 pairs) ----
  {
    const int sl = tid & 7, pL = tid >> 3;              // sl: float4 slot, pL: ic-pair 0..31
    const int gxm = x0 + 4*sl;                          // main cols 2+4sl .. 5+4sl
    const bool xokm = (unsigned)gxm <= 252u;
    const int gxe = x0 - 2;
    #pragma unroll
    for (int r = 0; r < 6; ++r) {
      const int gy = y0 - 2 + r;
      const bool yok = (unsigned)gy < 256u;
      #pragma unroll
      for (int ph = 0; ph < 2; ++ph) {
        const int p = pL + 32*ph;                       // ic pair 0..63
        const float* s0 = xb + (size_t)(2*p)*65536 + gy*256 + gxm;
        const bool ok = yok && xokm;
        f32x4 v0 = ok ? *(const f32x4*)s0 : f4z;
        f32x4 v1 = ok ? *(const f32x4*)(s0 + 65536) : f4z;
        char* wb = xls + (size_t)(((r*16 + (p>>2))*34 + 2 + 4*sl)*16 + (p&3)*4);
        #pragma unroll
        for (int i2 = 0; i2 < 4; ++i2) {
          uint32_t pk = ((uint32_t)f2bf(v1[i2]) << 16) | f2bf(v0[i2]);
          *(uint32_t*)(wb + i2*16) = pk;
        }
        if (sl == 0) {                                  // edge cols 0,1 (gx = x0-2, x0-1)
          const bool eok = yok && (gxe >= 0);
          const float* e0 = xb + (size_t)(2*p)*65536 + gy*256 + gxe;
          float e00 = eok ? e0[0] : 0.f, e01 = eok ? e0[1] : 0.f;
          float e10 = eok ? e0[65536] : 0.f, e11 = eok ? e0[65537] : 0.f;
          char* eb = xls + (size_t)(((r*16 + (p>>2))*34)*16 + (p&3)*4);
          *(uint32_t*)eb        = ((uint32_t)f2bf(e10) << 16) | f2bf(e00);
          *(uint32_t*)(eb + 16) = ((uint32_t)f2bf(e11) << 16) | f2bf(e01);
        }
      }
    }
  }
  __syncthreads();

  // ---- K-loop: 36 kidx; wf 3-deep (A/B/C rotation), xf JIT per cluster ----
  const int lane = tid & 63, wave = tid >> 6;
  const int wp = wave & 1, wo = wave >> 1;
  const int l15 = lane & 15, lq = lane >> 4;
  const short* wbase = wfrag + ((size_t)b*288 + wo*4)*512 + (size_t)lane*8;
  const int abase = ((wp*32 + lq)*34 + l15)*16;

  f32x4 acc[4][4] = {};
  bf16x8 wfA[4], wfB[4], wfC[4];

#define LDW(KI, WF) { const short* wp_ = wbase + (size_t)(KI)*4096;          \
    WF[0] = *(const bf16x8*)(wp_);       WF[1] = *(const bf16x8*)(wp_+512);  \
    WF[2] = *(const bf16x8*)(wp_+1024);  WF[3] = *(const bf16x8*)(wp_+1536); }

#define MFX(KI, WF) {                                                         \
    const int ch_ = (KI)/9, tp_ = (KI)%9, ky_ = tp_/3, kx_ = tp_%3;           \
    const int o00 = ((ky_*16 + ch_*4)*34 + kx_)*16;                           \
    const int o10 = o00 + 8704;                         /* +1 row = 16*34*16 */ \
    bf16x8 xf0 = *(const bf16x8*)(xls + abase + o00);                         \
    bf16x8 xf1 = *(const bf16x8*)(xls + abase + o00 + 256);                   \
    bf16x8 xf2 = *(const bf16x8*)(xls + abase + o10);                         \
    bf16x8 xf3 = *(const bf16x8*)(xls + abase + o10 + 256);                   \
    __builtin_amdgcn_s_setprio(1);                                            \
    acc[0][0] = __builtin_amdgcn_mfma_f32_16x16x32_bf16(xf0, WF[0], acc[0][0], 0,0,0); \
    acc[0][1] = __builtin_amdgcn_mfma_f32_16x16x32_bf16(xf0, WF[1], acc[0][1], 0,0,0); \
    acc[0][2] = __builtin_amdgcn_mfma_f32_16x16x32_bf16(xf0, WF[2], acc[0][2], 0,0,0); \
    acc[0][3] = __builtin_amdgcn_mfma_f32_16x16x32_bf16(xf0, WF[3], acc[0][3], 0,0,0); \
    acc[1][0] = __builtin_amdgcn_mfma_f32_16x16x32_bf16(xf1, WF[0], acc[1][0], 0,0,0); \
    acc[1][1] = __builtin_amdgcn_mfma_f32_16x16x32_bf16(xf1, WF[1], acc[1][1], 0,0,0); \
    acc[1][2] = __builtin_amdgcn_mfma_f32_16x16x32_bf16(xf1, WF[2], acc[1][2], 0,0,0); \
    acc[1][3] = __builtin_amdgcn_mfma_f32_16x16x32_bf16(xf1, WF[3], acc[1][3], 0,0,0); \
    acc[2][0] = __builtin_amdgcn_mfma_f32_16x16x32_bf16(xf2, WF[0], acc[2][0], 0,0,0); \
    acc[2][1] = __builtin_amdgcn_mfma_f32_16x16x32_bf16(xf2, WF[1], acc[2][1], 0,0,0); \
    acc[2][2] = __builtin_amdgcn_mfma_f32_16x16x32_bf16(xf2, WF[2], acc[2][2], 0,0,0); \
    acc[2][3] = __builtin_amdgcn_mfma_f32_16x16x32_bf16(xf2, WF[3], acc[2][3], 0,0,0); \
    acc[3][0] = __builtin_amdgcn_mfma_f32_16x16x32_bf16(xf3, WF[0], acc[3][0], 0,0,0); \
    acc[3][1] = __builtin_amdgcn_mfma_f32_16x16x32_bf16(xf3, WF[1], acc[3][1], 0,0,0); \
    acc[3][2] = __builtin_amdgcn_mfma_f32_16x16x32_bf16(xf3, WF[2], acc[3][2], 0,0,0); \
    acc[3][3] = __builtin_amdgcn_mfma_f32_16x16x32_bf16(xf3, WF[3], acc[3][3], 0,0,0); \
    __builtin_amdgcn_s_setprio(0); }

  LDW(0, wfA); LDW(1, wfB); LDW(2, wfC);
  #pragma unroll
  for (int kk = 0; kk < 36; kk += 3) {
    MFX(kk, wfA);
    if (kk + 3 < 36) LDW(kk + 3, wfA);
    MFX(kk + 1, wfB);
    if (kk + 4 < 36) LDW(kk + 4, wfB);
    MFX(kk + 2, wfC);
    if (kk + 5 < 36) LDW(kk + 5, wfC);
  }
#undef LDW
#undef MFX

  // ---- epilogue: lane holds px = x0+(p&1)*16+lq*4+j (contig), oc = wo*64+o*16+l15 ----
  #pragma unroll
  for (int p = 0; p < 4; ++p) {
    const int py = y0 + wp*2 + (p>>1);
    if (py >= 258) continue;
    const int px0 = x0 + (p&1)*16 + lq*4;
    #pragma unroll
    for (int o = 0; o < 4; ++o) {
      const int oc = wo*64 + o*16 + l15;
      const float bz = bias_lds[oc];
      f32x4 v = acc[p][o];
      v[0] += bz; v[1] += bz; v[2] += bz; v[3] += bz;
      float* dst = conv_out + ((size_t)(b*128 + oc)*258 + py)*258 + px0;
      if (px0 <= 254) {
        *(f32x4*)dst = v;
      } else {
        #pragma unroll
        for (int j = 0; j < 4; ++j)
          if (px0 + j < 258) dst[j] = v[j];
      }
    }
  }
}

// ---------------- fused up2x (sep) + lrelu/clamp + down2x (sep), 8-row strips ----------------
// (unchanged from round 11: packed-fp32 P1/P2, 256 threads)
__global__ __launch_bounds__(256) void updown_kernel(
    const float* __restrict__ conv_out,
    const float* __restrict__ upf, const float* __restrict__ dnf,
    float* __restrict__ down2)
{
  __shared__ float Bp[26][268];   // up1 strip; cols [4,262) live, zero pad sides
  __shared__ float Dp[8][524];    // down1 strip (522 live cols + pad)
  const int strip = blockIdx.x, c = blockIdx.y, b = blockIdx.z;
  const int y0 = strip * 8;
  const int tid = threadIdx.x;
  float fu[12], fd[12];
  #pragma unroll
  for (int k = 0; k < 12; ++k) { fu[k] = upf[11-k] * 2.0f; fd[k] = dnf[11-k]; }
  f32x2 fup[6];                   // (even-output tap, odd-output tap)
  #pragma unroll
  for (int j = 0; j < 6; ++j) fup[j] = (f32x2){fu[2*j+1], fu[2*j]};
  for (int e = tid; e < 260; e += 256) {
    int r = e / 10, pc = e % 10;
    int col = (pc < 4) ? pc : (258 + pc);
    Bp[r][col] = 0.f;
  }
  const float* src = conv_out + ((size_t)(b*128 + c)*258)*258;

  // P1: vertical upsample, packed row-pairs (v=2m, 2m+1 share inputs a[mp+j])
  #pragma unroll 1
  for (int m = tid; m < 258; m += 256) {
    float a[18];
    #pragma unroll
    for (int r = 0; r < 18; ++r) {
      int gy = y0 - 4 + r;
      a[r] = ((unsigned)gy < 258u) ? src[gy*258 + m] : 0.f;
    }
    #pragma unroll
    for (int mp = 0; mp < 13; ++mp) {
      f32x2 s2 = {0.f, 0.f};
      #pragma unroll
      for (int j = 0; j < 6; ++j) s2 += fup[j] * a[mp + j];
      Bp[2*mp][m + 4]     = s2[0];
      Bp[2*mp + 1][m + 4] = s2[1];
    }
  }
  __syncthreads();

  // P2: horizontal upsample (packed parity pair, shared window Bp[v][q..q+5])
  //     + lrelu(|x|) + packed vertical downsample
  const float LA = 0.84852813742386f;   // 0.6*sqrt(2)
  const float LB = 0.56568542494924f;   // 0.4*sqrt(2)
  #pragma unroll 1
  for (int q = tid; q < 261; q += 256) {
    f32x2 cc[26];
    #pragma unroll
    for (int v = 0; v < 26; ++v) {
      f32x2 c2 = {0.f, 0.f};
      #pragma unroll
      for (int j = 0; j < 6; ++j) c2 += fup[j] * Bp[v][q + j];
      f32x2 ab;
      ab[0] = __builtin_fabsf(c2[0]);
      ab[1] = __builtin_fabsf(c2[1]);
      c2 = LA*c2 + LB*ab;
      c2[0] = fminf(fmaxf(c2[0], -256.f), 256.f);
      c2[1] = fminf(fmaxf(c2[1], -256.f), 256.f);
      cc[v] = c2;
    }
    #pragma unroll
    for (int t = 0; t < 8; ++t) {
      f32x2 d = {0.f, 0.f};
      #pragma unroll
      for (int k = 0; k < 12; ++k) d += fd[k] * cc[2*t + k];
      *(f32x2*)&Dp[t][2*q] = d;
    }
  }
  __syncthreads();

  // P3: horizontal downsample, LDS -> global (8 rows x 32 threads/row)
  {
    const int ty = tid >> 5, xg = tid & 31;
    float* dstrow = down2 + ((size_t)(b*128 + c)*256 + (y0 + ty))*256;
    #pragma unroll
    for (int p = 0; p < 4; ++p) {
      const int pi = xg + 32*p;
      float fx[16];
      #pragma unroll
      for (int t = 0; t < 4; ++t)
        *(float4*)&fx[4*t] = *(const float4*)&Dp[ty][4*pi + 4*t];
      float o0 = 0.f, o1 = 0.f;
      #pragma unroll
      for (int k = 0; k < 12; ++k) {
        o0 += fd[k] * fx[k];
        o1 += fd[k] * fx[k + 2];
      }
      float2 st; st.x = o0; st.y = o1;
      *(float2*)&dstrow[2*pi] = st;
    }
  }
}

// ---------------- rgb: float4 per thread ----------------
__global__ __launch_bounds__(128) void rgb_kernel(
    const float* __restrict__ down2, const float* __restrict__ coef,
    const float* __restrict__ brgb, float* __restrict__ yout)
{
  __shared__ float cl[3][128];
  const int b = blockIdx.x >> 7;
  const int p4 = ((blockIdx.x & 127) << 7) + threadIdx.x;   // float4 idx 0..16383
  for (int e = threadIdx.x; e < 384; e += 128) cl[e >> 7][e & 127] = coef[b*384 + e];
  __syncthreads();
  f32x4 a0 = {0,0,0,0}, a1 = {0,0,0,0}, a2 = {0,0,0,0};
  const f32x4* dsrc = (const f32x4*)down2 + (size_t)b*2097152 + p4;
  #pragma unroll 4
  for (int i = 0; i < 128; ++i) {
    f32x4 v = dsrc[(size_t)i*16384];
    a0 += cl[0][i]*v; a1 += cl[1][i]*v; a2 += cl[2][i]*v;
  }
  f32x4* yo = (f32x4*)yout;
  const float b0 = brgb[0], b1 = brgb[1], b2 = brgb[2];
  #pragma unroll
  for (int j = 0; j < 4; ++j) {
    a0[j] = fminf(fmaxf(a0[j] + b0, -256.f), 256.f);
    a1[j] = fminf(fmaxf(a1[j] + b1, -256.f), 256.f);
    a2[j] = fminf(fmaxf(a2[j] + b2, -256.f), 256.f);
  }
  yo[(size_t)(b*3 + 0)*16384 + p4] = a0;
  yo[(size_t)(b*3 + 1)*16384 + p4] = a1;
  yo[(size_t)(b*3 + 2)*16384 + p4] = a2;
}

extern "C" void kernel_launch(void* const* d_in, const int* in_sizes, int n_in,
                              void* d_out, int out_size, void* d_ws, size_t ws_size,
                              hipStream_t stream) {
  const float* x      = (const float*)d_in[0];
  const float* w      = (const float*)d_in[1];
  const float* afw    = (const float*)d_in[2];
  const float* afb    = (const float*)d_in[3];
  const float* wfeat  = (const float*)d_in[4];
  const float* bfeat  = (const float*)d_in[5];
  const float* argbw  = (const float*)d_in[6];
  const float* argbb  = (const float*)d_in[7];
  const float* wrgb   = (const float*)d_in[8];
  const float* brgb   = (const float*)d_in[9];
  const float* upf    = (const float*)d_in[10];
  const float* dnf    = (const float*)d_in[11];
  const float* emaf   = (const float*)d_in[12];
  const float* emar   = (const float*)d_in[13];

  float* ws = (float*)d_ws;
  size_t off = 0;
  float* s_feat   = ws + off; off += 256;
  float* coef     = ws + off; off += 768;
  short* wfrag    = (short*)(ws + off); off += 147456;          // 294912 bf16
  float* conv_out = ws + off; off += (size_t)2*128*258*258;     // 17,040,384
  float* down2    = ws + off; off += (size_t)2*128*256*256;     // 16,777,216
  if (ws_size < off * sizeof(float)) return;
  float* yout = (float*)d_out;

  prep1_kernel<<<1, 256, 0, stream>>>(w, afw, afb, argbw, argbb, wrgb, emar,
                                      s_feat, coef);
  prep2_kernel<<<256, 128, 0, stream>>>(wfeat, s_feat, emaf, wfrag);
  conv_mfma_kernel<<<dim3(9, 65, 2), 256, 0, stream>>>(x, wfrag, bfeat, conv_out);
  updown_kernel<<<dim3(32, 128, 2), 256, 0, stream>>>(conv_out, upf, dnf, down2);
  rgb_kernel<<<256, 128, 0, stream>>>(down2, coef, brgb, yout);
}

// Round 13
// 226.453 us; speedup vs baseline: 1.4780x; 1.0099x over previous
//
#include <hip/hip_runtime.h>
#include <hip/hip_bf16.h>
#include <cstdint>

typedef __attribute__((ext_vector_type(8))) short bf16x8;
typedef __attribute__((ext_vector_type(4))) float f32x4;
typedef __attribute__((ext_vector_type(2))) float f32x2;

__device__ inline uint16_t f2bf(float f) {
  uint32_t u = __float_as_uint(f);
  u += 0x7FFF + ((u >> 16) & 1);          // round-to-nearest-even
  return (uint16_t)(u >> 16);
}

// ---------------- prep1: s_feat (RMS-normalized), rgb coefs ----------------
__global__ __launch_bounds__(256) void prep1_kernel(
    const float* __restrict__ w,        // (2,512)
    const float* __restrict__ afw,      // (128,512)
    const float* __restrict__ afb,      // (128)
    const float* __restrict__ argbw,    // (128,512)
    const float* __restrict__ argbb,    // (128)
    const float* __restrict__ wrgb,     // (3,128)
    const float* __restrict__ ema_r,    // (1)
    float* __restrict__ s_feat_out,     // (2,128)
    float* __restrict__ coef_out)       // (2,3,128)
{
  __shared__ float sfeat_s[256];
  __shared__ float srgb_s[256];
  __shared__ float sred[256];
  const int tid = threadIdx.x, lane = tid & 63, wv = tid >> 6;
  const float wg = 0.04419417382415922f;    // 1/sqrt(512)
  #pragma unroll 2
  for (int p = wv; p < 256; p += 4) {
    const int bb = p >> 7, c = p & 127;
    float d1 = 0.f, d2 = 0.f;
    #pragma unroll
    for (int it = 0; it < 8; ++it) {
      const int k = lane + 64*it;
      const float wvv = w[bb*512 + k];
      d1 += wvv * afw[c*512 + k];
      d2 += wvv * argbw[c*512 + k];
    }
    #pragma unroll
    for (int off = 32; off; off >>= 1) {
      d1 += __shfl_xor(d1, off, 64);
      d2 += __shfl_xor(d2, off, 64);
    }
    if (lane == 0) {
      sfeat_s[p] = d1 * wg + afb[c];
      srgb_s[p]  = (d2 * wg + argbb[c]) * 0.08838834764831845f * rsqrtf(ema_r[0]);
    }
  }
  __syncthreads();
  const float sf = sfeat_s[tid];
  sred[tid] = sf * sf;
  __syncthreads();
  for (int off = 128; off > 0; off >>= 1) {
    if (tid < off) sred[tid] += sred[tid + off];
    __syncthreads();
  }
  const float snorm = rsqrtf(sred[0] * (1.0f/256.0f));
  s_feat_out[tid] = sf * snorm;
  for (int e = tid; e < 768; e += 256) {
    int bb = e / 384, o = (e % 384) / 128, i = e & 127;
    coef_out[e] = wrgb[o*128 + i] * srgb_s[bb*128 + i];
  }
}

// ---------------- prep2: wnscale (inline) + modulate + demod -> bf16 fragments ----------------
// wfrag layout: [b][kidx 0..35][mglob 0..7][lane 0..63][j 0..7]  (short/bf16)
__global__ __launch_bounds__(128) void prep2_kernel(
    const float* __restrict__ wfeat, const float* __restrict__ s_feat,
    const float* __restrict__ ema_f, short* __restrict__ wfrag)
{
  __shared__ float red[128];
  const int bo = blockIdx.x, b = bo >> 7, o = bo & 127;
  const int i = threadIdx.x;
  float wraw[9]; float ssr = 0.f;
  #pragma unroll
  for (int j = 0; j < 9; ++j) { wraw[j] = wfeat[(o*128 + i)*9 + j]; ssr += wraw[j]*wraw[j]; }
  red[i] = ssr; __syncthreads();
  for (int off = 64; off > 0; off >>= 1) { if (i < off) red[i] += red[i+off]; __syncthreads(); }
  const float wsc = rsqrtf(red[0] * (1.0f/1152.0f));
  const float sv = s_feat[b*128 + i];
  float wr[9]; float ss = 0.f;
  #pragma unroll
  for (int j = 0; j < 9; ++j) { wr[j] = wraw[j] * wsc * sv; ss += wr[j]*wr[j]; }
  __syncthreads();
  red[i] = ss; __syncthreads();
  for (int off = 64; off > 0; off >>= 1) { if (i < off) red[i] += red[i+off]; __syncthreads(); }
  const float d = rsqrtf(red[0] + 1e-8f) * rsqrtf(ema_f[0]);
  const int chunk = i >> 5;
  const int lane = (o & 15) | (((i >> 3) & 3) << 4);
  const int jj = i & 7;
  #pragma unroll
  for (int tap = 0; tap < 9; ++tap) {
    int kidx = chunk*9 + tap;
    size_t sidx = ((((size_t)b*36 + kidx)*8 + (o >> 4)) << 9) + (lane << 3) + jj;
    wfrag[sidx] = (short)f2bf(wr[tap] * d);
  }
}

// ---------------- conv via bf16 MFMA implicit GEMM ----------------
// (byte-identical to round 12 — kept fixed so next round's counters diagnose it)
__global__ __launch_bounds__(256, 3) void conv_mfma_kernel(
    const float* __restrict__ x, const short* __restrict__ wfrag,
    const float* __restrict__ bias_feat, float* __restrict__ conv_out)
{
  __shared__ __align__(16) char xls[52224];
  __shared__ float bias_lds[128];
  const int tid = threadIdx.x;
  const int bx = blockIdx.x, by = blockIdx.y, b = blockIdx.z;
  const int x0 = bx * 32, y0 = by * 4;
  if (tid < 128) bias_lds[tid] = bias_feat[tid];

  const f32x4 f4z = {0.f, 0.f, 0.f, 0.f};
  const float* xb = x + (size_t)b * 8388608;

  // ---- stage x tile: 128 ic x 6 r x 34 c (fp32 -> bf16 pairs) ----
  {
    const int sl = tid & 7, pL = tid >> 3;              // sl: float4 slot, pL: ic-pair 0..31
    const int gxm = x0 + 4*sl;                          // main cols 2+4sl .. 5+4sl
    const bool xokm = (unsigned)gxm <= 252u;
    const int gxe = x0 - 2;
    #pragma unroll
    for (int r = 0; r < 6; ++r) {
      const int gy = y0 - 2 + r;
      const bool yok = (unsigned)gy < 256u;
      #pragma unroll
      for (int ph = 0; ph < 2; ++ph) {
        const int p = pL + 32*ph;                       // ic pair 0..63
        const float* s0 = xb + (size_t)(2*p)*65536 + gy*256 + gxm;
        const bool ok = yok && xokm;
        f32x4 v0 = ok ? *(const f32x4*)s0 : f4z;
        f32x4 v1 = ok ? *(const f32x4*)(s0 + 65536) : f4z;
        char* wb = xls + (size_t)(((r*16 + (p>>2))*34 + 2 + 4*sl)*16 + (p&3)*4);
        #pragma unroll
        for (int i2 = 0; i2 < 4; ++i2) {
          uint32_t pk = ((uint32_t)f2bf(v1[i2]) << 16) | f2bf(v0[i2]);
          *(uint32_t*)(wb + i2*16) = pk;
        }
        if (sl == 0) {                                  // edge cols 0,1 (gx = x0-2, x0-1)
          const bool eok = yok && (gxe >= 0);
          const float* e0 = xb + (size_t)(2*p)*65536 + gy*256 + gxe;
          float e00 = eok ? e0[0] : 0.f, e01 = eok ? e0[1] : 0.f;
          float e10 = eok ? e0[65536] : 0.f, e11 = eok ? e0[65537] : 0.f;
          char* eb = xls + (size_t)(((r*16 + (p>>2))*34)*16 + (p&3)*4);
          *(uint32_t*)eb        = ((uint32_t)f2bf(e10) << 16) | f2bf(e00);
          *(uint32_t*)(eb + 16) = ((uint32_t)f2bf(e11) << 16) | f2bf(e01);
        }
      }
    }
  }
  __syncthreads();

  // ---- K-loop: 36 kidx; wf 3-deep (A/B/C rotation), xf JIT per cluster ----
  const int lane = tid & 63, wave = tid >> 6;
  const int wp = wave & 1, wo = wave >> 1;
  const int l15 = lane & 15, lq = lane >> 4;
  const short* wbase = wfrag + ((size_t)b*288 + wo*4)*512 + (size_t)lane*8;
  const int abase = ((wp*32 + lq)*34 + l15)*16;

  f32x4 acc[4][4] = {};
  bf16x8 wfA[4], wfB[4], wfC[4];

#define LDW(KI, WF) { const short* wp_ = wbase + (size_t)(KI)*4096;          \
    WF[0] = *(const bf16x8*)(wp_);       WF[1] = *(const bf16x8*)(wp_+512);  \
    WF[2] = *(const bf16x8*)(wp_+1024);  WF[3] = *(const bf16x8*)(wp_+1536); }

#define MFX(KI, WF) {                                                         \
    const int ch_ = (KI)/9, tp_ = (KI)%9, ky_ = tp_/3, kx_ = tp_%3;           \
    const int o00 = ((ky_*16 + ch_*4)*34 + kx_)*16;                           \
    const int o10 = o00 + 8704;                         /* +1 row = 16*34*16 */ \
    bf16x8 xf0 = *(const bf16x8*)(xls + abase + o00);                         \
    bf16x8 xf1 = *(const bf16x8*)(xls + abase + o00 + 256);                   \
    bf16x8 xf2 = *(const bf16x8*)(xls + abase + o10);                         \
    bf16x8 xf3 = *(const bf16x8*)(xls + abase + o10 + 256);                   \
    __builtin_amdgcn_s_setprio(1);                                            \
    acc[0][0] = __builtin_amdgcn_mfma_f32_16x16x32_bf16(xf0, WF[0], acc[0][0], 0,0,0); \
    acc[0][1] = __builtin_amdgcn_mfma_f32_16x16x32_bf16(xf0, WF[1], acc[0][1], 0,0,0); \
    acc[0][2] = __builtin_amdgcn_mfma_f32_16x16x32_bf16(xf0, WF[2], acc[0][2], 0,0,0); \
    acc[0][3] = __builtin_amdgcn_mfma_f32_16x16x32_bf16(xf0, WF[3], acc[0][3], 0,0,0); \
    acc[1][0] = __builtin_amdgcn_mfma_f32_16x16x32_bf16(xf1, WF[0], acc[1][0], 0,0,0); \
    acc[1][1] = __builtin_amdgcn_mfma_f32_16x16x32_bf16(xf1, WF[1], acc[1][1], 0,0,0); \
    acc[1][2] = __builtin_amdgcn_mfma_f32_16x16x32_bf16(xf1, WF[2], acc[1][2], 0,0,0); \
    acc[1][3] = __builtin_amdgcn_mfma_f32_16x16x32_bf16(xf1, WF[3], acc[1][3], 0,0,0); \
    acc[2][0] = __builtin_amdgcn_mfma_f32_16x16x32_bf16(xf2, WF[0], acc[2][0], 0,0,0); \
    acc[2][1] = __builtin_amdgcn_mfma_f32_16x16x32_bf16(xf2, WF[1], acc[2][1], 0,0,0); \
    acc[2][2] = __builtin_amdgcn_mfma_f32_16x16x32_bf16(xf2, WF[2], acc[2][2], 0,0,0); \
    acc[2][3] = __builtin_amdgcn_mfma_f32_16x16x32_bf16(xf2, WF[3], acc[2][3], 0,0,0); \
    acc[3][0] = __builtin_amdgcn_mfma_f32_16x16x32_bf16(xf3, WF[0], acc[3][0], 0,0,0); \
    acc[3][1] = __builtin_amdgcn_mfma_f32_16x16x32_bf16(xf3, WF[1], acc[3][1], 0,0,0); \
    acc[3][2] = __builtin_amdgcn_mfma_f32_16x16x32_bf16(xf3, WF[2], acc[3][2], 0,0,0); \
    acc[3][3] = __builtin_amdgcn_mfma_f32_16x16x32_bf16(xf3, WF[3], acc[3][3], 0,0,0); \
    __builtin_amdgcn_s_setprio(0); }

  LDW(0, wfA); LDW(1, wfB); LDW(2, wfC);
  #pragma unroll
  for (int kk = 0; kk < 36; kk += 3) {
    MFX(kk, wfA);
    if (kk + 3 < 36) LDW(kk + 3, wfA);
    MFX(kk + 1, wfB);
    if (kk + 4 < 36) LDW(kk + 4, wfB);
    MFX(kk + 2, wfC);
    if (kk + 5 < 36) LDW(kk + 5, wfC);
  }
#undef LDW
#undef MFX

  // ---- epilogue: lane holds px = x0+(p&1)*16+lq*4+j (contig), oc = wo*64+o*16+l15 ----
  #pragma unroll
  for (int p = 0; p < 4; ++p) {
    const int py = y0 + wp*2 + (p>>1);
    if (py >= 258) continue;
    const int px0 = x0 + (p&1)*16 + lq*4;
    #pragma unroll
    for (int o = 0; o < 4; ++o) {
      const int oc = wo*64 + o*16 + l15;
      const float bz = bias_lds[oc];
      f32x4 v = acc[p][o];
      v[0] += bz; v[1] += bz; v[2] += bz; v[3] += bz;
      float* dst = conv_out + ((size_t)(b*128 + oc)*258 + py)*258 + px0;
      if (px0 <= 254) {
        *(f32x4*)dst = v;
      } else {
        #pragma unroll
        for (int j = 0; j < 4; ++j)
          if (px0 + j < 258) dst[j] = v[j];
      }
    }
  }
}

// ---------------- fused up2x (sep) + lrelu/clamp + down2x (sep), 8-row strips ----------------
// P2 q-pair: thread t2 handles q=2*t2, 2*t2+1 via shared 8-float window (4x ds_read_b64),
// packed-fp32 throughout, streaming dA/dB accumulators, b128 Dp writes.
__global__ __launch_bounds__(256) void updown_kernel(
    const float* __restrict__ conv_out,
    const float* __restrict__ upf, const float* __restrict__ dnf,
    float* __restrict__ down2)
{
  __shared__ float Bp[26][268];   // up1 strip; cols [4,262) live, zero pad both sides
  __shared__ float Dp[8][524];    // down1 strip (522 live cols + 2 pad)
  const int strip = blockIdx.x, c = blockIdx.y, b = blockIdx.z;
  const int y0 = strip * 8;
  const int tid = threadIdx.x;
  float fu[12], fd[12];
  #pragma unroll
  for (int k = 0; k < 12; ++k) { fu[k] = upf[11-k] * 2.0f; fd[k] = dnf[11-k]; }
  f32x2 fup[6];                   // (even-output tap, odd-output tap)
  #pragma unroll
  for (int j = 0; j < 6; ++j) fup[j] = (f32x2){fu[2*j+1], fu[2*j]};
  for (int e = tid; e < 260; e += 256) {
    int r = e / 10, pc = e % 10;
    int col = (pc < 4) ? pc : (258 + pc);
    Bp[r][col] = 0.f;
  }
  const float* src = conv_out + ((size_t)(b*128 + c)*258)*258;

  // P1: vertical upsample, packed row-pairs (v=2m, 2m+1 share inputs a[mp+j])
  #pragma unroll 1
  for (int m = tid; m < 258; m += 256) {
    float a[18];
    #pragma unroll
    for (int r = 0; r < 18; ++r) {
      int gy = y0 - 4 + r;
      a[r] = ((unsigned)gy < 258u) ? src[gy*258 + m] : 0.f;
    }
    #pragma unroll
    for (int mp = 0; mp < 13; ++mp) {
      f32x2 s2 = {0.f, 0.f};
      #pragma unroll
      for (int j = 0; j < 6; ++j) s2 += fup[j] * a[mp + j];
      Bp[2*mp][m + 4]     = s2[0];
      Bp[2*mp + 1][m + 4] = s2[1];
    }
  }
  __syncthreads();

  // P2: q-pair horizontal upsample + lrelu + streaming vertical downsample.
  // Thread t2 < 131: q_e = 2*t2 (window w[0..5]), q_o = 2*t2+1 (window w[1..6]).
  // Window = Bp[v][2*t2 .. 2*t2+7] via 4x b64. Pad cols (262..267 zeroed) make
  // t2=130 safe; its q_o=261 result lands in Dp cols 522/523 (never consumed).
  const float LA = 0.84852813742386f;   // 0.6*sqrt(2)
  const float LB = 0.56568542494924f;   // 0.4*sqrt(2)
  if (tid < 131) {
    const int t2 = tid;
    f32x2 dA[8], dB[8];
    #pragma unroll
    for (int t = 0; t < 8; ++t) { dA[t] = (f32x2){0.f,0.f}; dB[t] = (f32x2){0.f,0.f}; }
    #pragma unroll
    for (int v = 0; v < 26; ++v) {
      float f[8];
      #pragma unroll
      for (int j2 = 0; j2 < 4; ++j2)
        *(float2*)&f[2*j2] = *(const float2*)&Bp[v][2*t2 + 2*j2];
      f32x2 ce = {0.f, 0.f}, co = {0.f, 0.f};
      #pragma unroll
      for (int j = 0; j < 6; ++j) { ce += fup[j] * f[j]; co += fup[j] * f[j+1]; }
      f32x2 abe, abo;
      abe[0] = __builtin_fabsf(ce[0]); abe[1] = __builtin_fabsf(ce[1]);
      abo[0] = __builtin_fabsf(co[0]); abo[1] = __builtin_fabsf(co[1]);
      ce = LA*ce + LB*abe;
      co = LA*co + LB*abo;
      ce[0] = fminf(fmaxf(ce[0], -256.f), 256.f);
      ce[1] = fminf(fmaxf(ce[1], -256.f), 256.f);
      co[0] = fminf(fmaxf(co[0], -256.f), 256.f);
      co[1] = fminf(fmaxf(co[1], -256.f), 256.f);
      #pragma unroll
      for (int t = 0; t < 8; ++t) {
        const int k = v - 2*t;                 // compile-time under full unroll
        if (k >= 0 && k < 12) { dA[t] += fd[k]*ce; dB[t] += fd[k]*co; }
      }
    }
    #pragma unroll
    for (int t = 0; t < 8; ++t) {
      f32x4 st4;
      st4[0] = dA[t][0]; st4[1] = dA[t][1];
      st4[2] = dB[t][0]; st4[3] = dB[t][1];
      *(f32x4*)&Dp[t][4*t2] = st4;             // 16B-aligned (row stride 524*4, col 16*t2)
    }
  }
  __syncthreads();

  // P3: horizontal downsample, LDS -> global (8 rows x 32 threads/row)
  {
    const int ty = tid >> 5, xg = tid & 31;
    float* dstrow = down2 + ((size_t)(b*128 + c)*256 + (y0 + ty))*256;
    #pragma unroll
    for (int p = 0; p < 4; ++p) {
      const int pi = xg + 32*p;
      float fx[16];
      #pragma unroll
      for (int t = 0; t < 4; ++t)
        *(float4*)&fx[4*t] = *(const float4*)&Dp[ty][4*pi + 4*t];
      float o0 = 0.f, o1 = 0.f;
      #pragma unroll
      for (int k = 0; k < 12; ++k) {
        o0 += fd[k] * fx[k];
        o1 += fd[k] * fx[k + 2];
      }
      float2 st; st.x = o0; st.y = o1;
      *(float2*)&dstrow[2*pi] = st;
    }
  }
}

// ---------------- rgb: float4 per thread ----------------
__global__ __launch_bounds__(128) void rgb_kernel(
    const float* __restrict__ down2, const float* __restrict__ coef,
    const float* __restrict__ brgb, float* __restrict__ yout)
{
  __shared__ float cl[3][128];
  const int b = blockIdx.x >> 7;
  const int p4 = ((blockIdx.x & 127) << 7) + threadIdx.x;   // float4 idx 0..16383
  for (int e = threadIdx.x; e < 384; e += 128) cl[e >> 7][e & 127] = coef[b*384 + e];
  __syncthreads();
  f32x4 a0 = {0,0,0,0}, a1 = {0,0,0,0}, a2 = {0,0,0,0};
  const f32x4* dsrc = (const f32x4*)down2 + (size_t)b*2097152 + p4;
  #pragma unroll 4
  for (int i = 0; i < 128; ++i) {
    f32x4 v = dsrc[(size_t)i*16384];
    a0 += cl[0][i]*v; a1 += cl[1][i]*v; a2 += cl[2][i]*v;
  }
  f32x4* yo = (f32x4*)yout;
  const float b0 = brgb[0], b1 = brgb[1], b2 = brgb[2];
  #pragma unroll
  for (int j = 0; j < 4; ++j) {
    a0[j] = fminf(fmaxf(a0[j] + b0, -256.f), 256.f);
    a1[j] = fminf(fmaxf(a1[j] + b1, -256.f), 256.f);
    a2[j] = fminf(fmaxf(a2[j] + b2, -256.f), 256.f);
  }
  yo[(size_t)(b*3 + 0)*16384 + p4] = a0;
  yo[(size_t)(b*3 + 1)*16384 + p4] = a1;
  yo[(size_t)(b*3 + 2)*16384 + p4] = a2;
}

extern "C" void kernel_launch(void* const* d_in, const int* in_sizes, int n_in,
                              void* d_out, int out_size, void* d_ws, size_t ws_size,
                              hipStream_t stream) {
  const float* x      = (const float*)d_in[0];
  const float* w      = (const float*)d_in[1];
  const float* afw    = (const float*)d_in[2];
  const float* afb    = (const float*)d_in[3];
  const float* wfeat  = (const float*)d_in[4];
  const float* bfeat  = (const float*)d_in[5];
  const float* argbw  = (const float*)d_in[6];
  const float* argbb  = (const float*)d_in[7];
  const float* wrgb   = (const float*)d_in[8];
  const float* brgb   = (const float*)d_in[9];
  const float* upf    = (const float*)d_in[10];
  const float* dnf    = (const float*)d_in[11];
  const float* emaf   = (const float*)d_in[12];
  const float* emar   = (const float*)d_in[13];

  float* ws = (float*)d_ws;
  size_t off = 0;
  float* s_feat   = ws + off; off += 256;
  float* coef     = ws + off; off += 768;
  short* wfrag    = (short*)(ws + off); off += 147456;          // 294912 bf16
  float* conv_out = ws + off; off += (size_t)2*128*258*258;     // 17,040,384
  float* down2    = ws + off; off += (size_t)2*128*256*256;     // 16,777,216
  if (ws_size < off * sizeof(float)) return;
  float* yout = (float*)d_out;

  prep1_kernel<<<1, 256, 0, stream>>>(w, afw, afb, argbw, argbb, wrgb, emar,
                                      s_feat, coef);
  prep2_kernel<<<256, 128, 0, stream>>>(wfeat, s_feat, emaf, wfrag);
  conv_mfma_kernel<<<dim3(9, 65, 2), 256, 0, stream>>>(x, wfrag, bfeat, conv_out);
  updown_kernel<<<dim3(32, 128, 2), 256, 0, stream>>>(conv_out, upf, dnf, down2);
  rgb_kernel<<<256, 128, 0, stream>>>(down2, coef, brgb, yout);
}